// Round 7
// baseline (240.299 us; speedup 1.0000x reference)
//
#include <hip/hip_runtime.h>
#include <hip/hip_bf16.h>
#include <math.h>

#define B 4
#define T 512
#define D 256
#define H 8
#define BH (B*H)
#define SCALE 0.0625f

typedef float f32x4 __attribute__((ext_vector_type(4)));
typedef short bf16x8 __attribute__((ext_vector_type(8)));
typedef _Float16 f16x2 __attribute__((ext_vector_type(2)));

__device__ __forceinline__ ushort f2b(float f) {
    __hip_bfloat16 h = __float2bfloat16(f);
    return *reinterpret_cast<ushort*>(&h);
}
__device__ __forceinline__ float b2f(ushort u) {
    __hip_bfloat16 h;
    *reinterpret_cast<ushort*>(&h) = u;
    return __bfloat162float(h);
}
__device__ __forceinline__ ushort f2h(float f) {
    _Float16 h = (_Float16)f;
    ushort u; __builtin_memcpy(&u, &h, 2); return u;
}
// single-instruction packed-f16 ops (one inst per asm so scheduler interleaves)
__device__ __forceinline__ uint hmax2u(uint a, uint b) {
    uint d; asm("v_pk_max_f16 %0, %1, %2" : "=v"(d) : "v"(a), "v"(b)); return d;
}
__device__ __forceinline__ uint hadd2u(uint a, uint b) {
    uint d; asm("v_pk_add_f16 %0, %1, %2" : "=v"(d) : "v"(a), "v"(b)); return d;
}
__device__ __forceinline__ uint hmul2u(uint a, uint b) {
    uint d; asm("v_pk_mul_f16 %0, %1, %2" : "=v"(d) : "v"(a), "v"(b)); return d;
}
__device__ __forceinline__ float h2lo(uint u) {
    f16x2 t = __builtin_bit_cast(f16x2, u); return (float)t[0];
}
__device__ __forceinline__ float h2hi(uint u) {
    f16x2 t = __builtin_bit_cast(f16x2, u); return (float)t[1];
}

// ---- K0: x -> bf16 + f16; wqv_w -> bf16; wk -> f16; zero Qsum/rsum/csum ----
__global__ __launch_bounds__(256) void k0_convert(const float* __restrict__ x,
        const float* __restrict__ w, const float* __restrict__ wk,
        ushort* __restrict__ xb, ushort* __restrict__ xh,
        ushort* __restrict__ wb, ushort* __restrict__ wkh,
        float* __restrict__ rszero, float* __restrict__ Qsum) {
    int bx = blockIdx.x;
    if (bx < 32) {          // zero rsum+csum (32768 floats)
        ((float4*)rszero)[bx*256 + threadIdx.x] = make_float4(0.f,0.f,0.f,0.f);
    } else if (bx < 48) {   // zero Qsum (16384 floats)
        ((float4*)Qsum)[(bx-32)*256 + threadIdx.x] = make_float4(0.f,0.f,0.f,0.f);
    }
    int i = bx * 256 + threadIdx.x;
    if (i < 131072) {
        float4 v = ((const float4*)x)[i];
        ((ushort4*)xb)[i] = make_ushort4(f2b(v.x), f2b(v.y), f2b(v.z), f2b(v.w));
        ((ushort4*)xh)[i] = make_ushort4(f2h(v.x), f2h(v.y), f2h(v.z), f2h(v.w));
    } else if (i < 524288) {
        int j = i - 131072;
        float4 v = ((const float4*)w)[j];
        ((ushort4*)wb)[j] = make_ushort4(f2b(v.x), f2b(v.y), f2b(v.z), f2b(v.w));
    } else if (i < 524288 + 512) {
        int j = i - 524288;
        float4 v = ((const float4*)wk)[j];
        ((ushort4*)wkh)[j] = make_ushort4(f2h(v.x), f2h(v.y), f2h(v.z), f2h(v.w));
    }
}

// ---- K2a: Ksum[bh][d] = sum_w f16(xh*wkh) (f16-consistent with k2 inner) ---
__global__ __launch_bounds__(256) void k2a_sums(const ushort* __restrict__ xh,
        const uint* __restrict__ wkh, float* __restrict__ Ksum) {
    int row = blockIdx.x * 4 + (threadIdx.x >> 6);   // 0..16383 = bh*512 + d
    int lane = threadIdx.x & 63;
    int b_ = row >> 12, h_ = (row >> 9) & 7, d_ = row & 511;
    uint2 xu = *(const uint2*)&xh[((size_t)(b_*T + d_))*D + lane*4];
    uint2 wv = *(const uint2*)&wkh[h_*128 + lane*2];
    uint p0 = hmul2u(xu.x, wv.x);
    uint p1 = hmul2u(xu.y, wv.y);
    float s = h2lo(p0) + h2hi(p0) + h2lo(p1) + h2hi(p1);
    #pragma unroll
    for (int o = 32; o > 0; o >>= 1) s += __shfl_xor(s, o);
    if (lane == 0) Ksum[row] = s;
}

// ---- K1: bf16 MFMA GEMM  v = x @ wqv^T + bias ------------------------------
// ALL outputs via LDS transpose: q(f16) [bh][w][t], vf/vb(bf16) [bh][w][t].
// Qsum[bh][t] = sum_w q fused via shfl+atomics (f32; negligible vs f16 id).
__global__ __launch_bounds__(256) void k1_qkv(const ushort* __restrict__ xb,
        const ushort* __restrict__ wb, const float* __restrict__ bias,
        ushort* __restrict__ qT, ushort* __restrict__ vf, ushort* __restrict__ vb,
        float* __restrict__ Qsum) {
    __shared__ ushort AB[2*128*40];
    ushort* As = AB;
    ushort* Bs = AB + 128*40;
    int tid = threadIdx.x;
    int lane = tid & 63, wave = tid >> 6;
    int wm = wave >> 1, wn = wave & 1;
    int bm0 = blockIdx.x * 128, bn0 = blockIdx.y * 128;
    f32x4 acc[4][4] = {};
    int sr = tid >> 2, sc = (tid & 3) * 8;
    int fr = lane & 15, fg = (lane >> 4) * 8;
    for (int k0 = 0; k0 < 256; k0 += 32) {
        *(uint4*)&As[sr*40 + sc]      = *(const uint4*)&xb[(size_t)(bm0+sr)*256 + k0 + sc];
        *(uint4*)&As[(sr+64)*40 + sc] = *(const uint4*)&xb[(size_t)(bm0+sr+64)*256 + k0 + sc];
        *(uint4*)&Bs[sr*40 + sc]      = *(const uint4*)&wb[(size_t)(bn0+sr)*256 + k0 + sc];
        *(uint4*)&Bs[(sr+64)*40 + sc] = *(const uint4*)&wb[(size_t)(bn0+sr+64)*256 + k0 + sc];
        __syncthreads();
        bf16x8 af[4], bfv[4];
        #pragma unroll
        for (int i = 0; i < 4; ++i)
            af[i] = *(const bf16x8*)&As[(wm*64 + i*16 + fr)*40 + fg];
        #pragma unroll
        for (int i = 0; i < 4; ++i)
            bfv[i] = *(const bf16x8*)&Bs[(wn*64 + i*16 + fr)*40 + fg];
        #pragma unroll
        for (int mi = 0; mi < 4; ++mi)
            #pragma unroll
            for (int ni = 0; ni < 4; ++ni)
                acc[mi][ni] = __builtin_amdgcn_mfma_f32_16x16x32_bf16(af[mi], bfv[ni], acc[mi][ni], 0, 0, 0);
        __syncthreads();
    }
    int fq = lane >> 4;
    int g = bn0 >> 11;
    int b_ = bm0 >> 9;
    int t0base = bm0 & 511;
    float bn_[4];
    #pragma unroll
    for (int ni = 0; ni < 4; ++ni) bn_[ni] = bias[bn0 + wn*64 + ni*16 + fr];

    if (g == 0) {   // Qsum partials: t fixed across fr-lanes
        int h_ = bn0 >> 8;
        #pragma unroll
        for (int mi = 0; mi < 4; ++mi)
            #pragma unroll
            for (int r = 0; r < 4; ++r) {
                float v = (acc[mi][0][r]+bn_[0]) + (acc[mi][1][r]+bn_[1])
                        + (acc[mi][2][r]+bn_[2]) + (acc[mi][3][r]+bn_[3]);
                v += __shfl_xor(v, 1); v += __shfl_xor(v, 2);
                v += __shfl_xor(v, 4); v += __shfl_xor(v, 8);
                if (fr == 0)
                    atomicAdd(&Qsum[(b_*H + h_)*T + t0base + wm*64 + mi*16 + fq*4 + r], v);
            }
    }
    // transpose epilogue: tb = [64 n-half][132 m]
    ushort* dstbase = (g == 0) ? qT : (g == 1 ? vf : vb);
    ushort* tb = AB;
    #pragma unroll
    for (int hf = 0; hf < 2; ++hf) {
        __syncthreads();
        if (wn == hf) {
            #pragma unroll
            for (int ni = 0; ni < 4; ++ni) {
                int nh = ni*16 + fr;
                #pragma unroll
                for (int mi = 0; mi < 4; ++mi) {
                    int mloc = wm*64 + mi*16 + fq*4;
                    float v0 = acc[mi][ni][0] + bn_[ni];
                    float v1 = acc[mi][ni][1] + bn_[ni];
                    float v2 = acc[mi][ni][2] + bn_[ni];
                    float v3 = acc[mi][ni][3] + bn_[ni];
                    *(ushort4*)&tb[nh*132 + mloc] = (g == 0)
                        ? make_ushort4(f2h(v0), f2h(v1), f2h(v2), f2h(v3))
                        : make_ushort4(f2b(v0), f2b(v1), f2b(v2), f2b(v3));
                }
            }
        }
        __syncthreads();
        #pragma unroll
        for (int p = 0; p < 2; ++p) {
            int rr = tid >> 2;
            int cc = (tid & 3)*16 + p*64;
            const ushort* src = &tb[rr*132 + cc];
            uint2 a0 = *(const uint2*)(src);
            uint2 a1 = *(const uint2*)(src + 4);
            uint2 a2 = *(const uint2*)(src + 8);
            uint2 a3 = *(const uint2*)(src + 12);
            int n = bn0 + hf*64 + rr;
            int h_ = (n & 2047) >> 8, w_ = n & 255;
            ushort* dst = dstbase + ((size_t)(b_*H + h_)*D + w_)*T + t0base + cc;
            *(uint4*)dst       = make_uint4(a0.x, a0.y, a1.x, a1.y);
            *(uint4*)(dst + 8) = make_uint4(a2.x, a2.y, a3.x, a3.y);
        }
    }
}

// ---- K2: E = exp(-SCALE*(2*sum max(q,k) - Qsum - Ksum)); E, Et, rsum, csum -
// q from [bh][w][t]: pair-pack via v_perm -> b128 LDS writes. Prefetched loads.
__global__ __launch_bounds__(256) void k2_scores(const ushort* __restrict__ qT,
        const ushort* __restrict__ xh, const uint* __restrict__ wkh,
        const float* __restrict__ Qsum, const float* __restrict__ Ksum,
        ushort* __restrict__ E, ushort* __restrict__ Et,
        float* __restrict__ rsum, float* __restrict__ csum) {
    __shared__ uint SM[6272];
    __shared__ float cspart[64];
    uint* Qs = SM;            // [32 up][128 s] stride 130
    uint* Ks = SM + 4160;     // [32 up][64 d]  stride 66
    int s0 = blockIdx.x * 128, d0 = blockIdx.y * 64, bh = blockIdx.z;
    int b_ = bh >> 3, h_ = bh & 7;
    int tid = threadIdx.x;
    int tx = tid & 15, ty = tid >> 4;
    const ushort* qbb = qT + (size_t)bh * D * T;
    const ushort* xbb = xh + (size_t)b_ * T * D;
    if (tid < 64) cspart[tid] = 0.f;
    int rp = tid >> 3;            // 0..31 w-pair (Q staging)
    int tc = (tid & 7) * 16;      // s-chunk
    int dr = tid >> 2;            // 0..63 d-row (K staging)
    int cb = (tid & 3) * 16;      // w-chunk within 64
    int up0 = cb >> 1;
    uint4 qa0,qa1,qb0,qb1, xv0,xv1, wv0,wv1;
    float accf[8][4] = {};
    {   // initial loads (chunk 0)
        const ushort* qr = &qbb[(size_t)(2*rp)*T + s0 + tc];
        qa0 = *(const uint4*)qr; qa1 = *(const uint4*)(qr+8);
        qb0 = *(const uint4*)(qr+T); qb1 = *(const uint4*)(qr+T+8);
        const ushort* xr = &xbb[(size_t)(d0+dr)*D + cb];
        xv0 = *(const uint4*)xr; xv1 = *(const uint4*)(xr+8);
        const uint* wp = &wkh[h_*128 + (cb>>1)];
        wv0 = *(const uint4*)wp; wv1 = *(const uint4*)(wp+4);
    }
    for (int c = 0; c < 4; ++c) {
        if (c) __syncthreads();
        {   // Q: pair-pack (w,w+1) and write 4 x b128
            uint av[8] = {qa0.x,qa0.y,qa0.z,qa0.w,qa1.x,qa1.y,qa1.z,qa1.w};
            uint bv[8] = {qb0.x,qb0.y,qb0.z,qb0.w,qb1.x,qb1.y,qb1.z,qb1.w};
            uint o[16];
            #pragma unroll
            for (int j = 0; j < 8; ++j) {
                o[2*j]   = __builtin_amdgcn_perm(bv[j], av[j], 0x05040100u);
                o[2*j+1] = __builtin_amdgcn_perm(bv[j], av[j], 0x07060302u);
            }
            uint* qdst = &Qs[rp*130 + tc];
            *(uint4*)(qdst)      = make_uint4(o[0],o[1],o[2],o[3]);
            *(uint4*)(qdst + 4)  = make_uint4(o[4],o[5],o[6],o[7]);
            *(uint4*)(qdst + 8)  = make_uint4(o[8],o[9],o[10],o[11]);
            *(uint4*)(qdst + 12) = make_uint4(o[12],o[13],o[14],o[15]);
        }
        {   // K: k = f16(x*wk)
            Ks[(up0+0)*66 + dr] = hmul2u(xv0.x, wv0.x);
            Ks[(up0+1)*66 + dr] = hmul2u(xv0.y, wv0.y);
            Ks[(up0+2)*66 + dr] = hmul2u(xv0.z, wv0.z);
            Ks[(up0+3)*66 + dr] = hmul2u(xv0.w, wv0.w);
            Ks[(up0+4)*66 + dr] = hmul2u(xv1.x, wv1.x);
            Ks[(up0+5)*66 + dr] = hmul2u(xv1.y, wv1.y);
            Ks[(up0+6)*66 + dr] = hmul2u(xv1.z, wv1.z);
            Ks[(up0+7)*66 + dr] = hmul2u(xv1.w, wv1.w);
        }
        __syncthreads();
        if (c < 3) {   // prefetch next chunk under compute
            int w0 = (c+1)*64;
            const ushort* qr = &qbb[(size_t)(w0 + 2*rp)*T + s0 + tc];
            qa0 = *(const uint4*)qr; qa1 = *(const uint4*)(qr+8);
            qb0 = *(const uint4*)(qr+T); qb1 = *(const uint4*)(qr+T+8);
            const ushort* xr = &xbb[(size_t)(d0+dr)*D + w0 + cb];
            xv0 = *(const uint4*)xr; xv1 = *(const uint4*)(xr+8);
            const uint* wp = &wkh[h_*128 + ((w0+cb)>>1)];
            wv0 = *(const uint4*)wp; wv1 = *(const uint4*)(wp+4);
        }
        uint acc2[8][4];
        #pragma unroll
        for (int i = 0; i < 8; ++i)
            #pragma unroll
            for (int j = 0; j < 4; ++j) acc2[i][j] = 0u;
        #pragma unroll 2
        for (int up = 0; up < 32; ++up) {
            const uint* qrow = &Qs[up*130 + ty*8];
            uint2 qa = *(const uint2*)qrow;
            uint2 qb2 = *(const uint2*)(qrow + 2);
            uint2 qc = *(const uint2*)(qrow + 4);
            uint2 qd = *(const uint2*)(qrow + 6);
            const uint* krow = &Ks[up*66 + tx*4];
            uint2 ka = *(const uint2*)krow;
            uint2 kb = *(const uint2*)(krow + 2);
            uint q8[8] = {qa.x, qa.y, qb2.x, qb2.y, qc.x, qc.y, qd.x, qd.y};
            uint k4v[4] = {ka.x, ka.y, kb.x, kb.y};
            #pragma unroll
            for (int i = 0; i < 8; ++i)
                #pragma unroll
                for (int j = 0; j < 4; ++j)
                    acc2[i][j] = hadd2u(acc2[i][j], hmax2u(q8[i], k4v[j]));
        }
        #pragma unroll
        for (int i = 0; i < 8; ++i)
            #pragma unroll
            for (int j = 0; j < 4; ++j)
                accf[i][j] += h2lo(acc2[i][j]) + h2hi(acc2[i][j]);
    }
    // ---- epilogue: e = exp(-SCALE*(2M - Qsum - Ksum)) ----
    float qs8[8], ks4[4];
    {
        float4 qlo = *(const float4*)&Qsum[bh*T + s0 + ty*8];
        float4 qhi = *(const float4*)&Qsum[bh*T + s0 + ty*8 + 4];
        qs8[0]=qlo.x; qs8[1]=qlo.y; qs8[2]=qlo.z; qs8[3]=qlo.w;
        qs8[4]=qhi.x; qs8[5]=qhi.y; qs8[6]=qhi.z; qs8[7]=qhi.w;
        float4 kv = *(const float4*)&Ksum[bh*T + d0 + tx*4];
        ks4[0]=kv.x; ks4[1]=kv.y; ks4[2]=kv.z; ks4[3]=kv.w;
    }
    #pragma unroll
    for (int i = 0; i < 8; ++i)
        #pragma unroll
        for (int j = 0; j < 4; ++j)
            accf[i][j] = __expf(-SCALE * (2.f*accf[i][j] - qs8[i] - ks4[j]));
    #pragma unroll
    for (int i = 0; i < 8; ++i)
        *(ushort4*)&E[((size_t)bh*T + s0 + ty*8 + i)*T + d0 + tx*4] =
            make_ushort4(f2b(accf[i][0]), f2b(accf[i][1]), f2b(accf[i][2]), f2b(accf[i][3]));
    #pragma unroll
    for (int i = 0; i < 8; ++i) {
        float rs = accf[i][0] + accf[i][1] + accf[i][2] + accf[i][3];
        rs += __shfl_xor(rs, 1); rs += __shfl_xor(rs, 2);
        rs += __shfl_xor(rs, 4); rs += __shfl_xor(rs, 8);
        if ((tid & 15) == 0) atomicAdd(&rsum[bh*T + s0 + ty*8 + i], rs);
    }
    #pragma unroll
    for (int j = 0; j < 4; ++j) {
        float cs = 0.f;
        #pragma unroll
        for (int i = 0; i < 8; ++i) cs += accf[i][j];
        atomicAdd(&cspart[tx*4 + j], cs);
    }
    __syncthreads();
    ushort* tb = (ushort*)SM;   // [64 d][132 s]
    #pragma unroll
    for (int j = 0; j < 4; ++j) {
        int drow = tx*4 + j;
        *(ushort4*)&tb[drow*132 + ty*8] = make_ushort4(
            f2b(accf[0][j]), f2b(accf[1][j]), f2b(accf[2][j]), f2b(accf[3][j]));
        *(ushort4*)&tb[drow*132 + ty*8 + 4] = make_ushort4(
            f2b(accf[4][j]), f2b(accf[5][j]), f2b(accf[6][j]), f2b(accf[7][j]));
    }
    if (tid < 64) atomicAdd(&csum[bh*T + d0 + tid], cspart[tid]);
    __syncthreads();
    #pragma unroll
    for (int p = 0; p < 2; ++p) {
        int rr = (tid >> 3) + p*32;
        int sc = (tid & 7) * 16;
        const ushort* src = &tb[rr*132 + sc];
        uint2 a0 = *(const uint2*)(src);
        uint2 a1 = *(const uint2*)(src + 4);
        uint2 a2 = *(const uint2*)(src + 8);
        uint2 a3 = *(const uint2*)(src + 12);
        ushort* dst = &Et[((size_t)bh*T + d0 + rr)*T + s0 + sc];
        *(uint4*)dst       = make_uint4(a0.x, a0.y, a1.x, a1.y);
        *(uint4*)(dst + 8) = make_uint4(a2.x, a2.y, a3.x, a3.y);
    }
}

// ---- K4: dual bf16 MFMA GEMM: part[bh][d][w] = (Et.Vf)/csum[d] + (E.Vb)/rsum[d]
__global__ __launch_bounds__(256) void k4_attn(const ushort* __restrict__ E,
        const ushort* __restrict__ Et, const ushort* __restrict__ vfT,
        const ushort* __restrict__ vbT, const float* __restrict__ rsum,
        const float* __restrict__ csum, float* __restrict__ part) {
    __shared__ ushort A1[128*40];
    __shared__ ushort A2[128*40];
    __shared__ ushort Bf[64*40];
    __shared__ ushort Bb[64*40];
    int d0 = blockIdx.x * 128, w0 = blockIdx.y * 64, bh = blockIdx.z;
    const ushort* Ebb = E  + (size_t)bh*T*T;
    const ushort* Etb = Et + (size_t)bh*T*T;
    const ushort* vfb = vfT + (size_t)bh*D*T;
    const ushort* vbb = vbT + (size_t)bh*D*T;
    int tid = threadIdx.x, lane = tid & 63, wave = tid >> 6;
    int wm = wave >> 1, wn = wave & 1;
    int sr = tid >> 2, sc = (tid & 3) * 8;
    int fr = lane & 15, fg = (lane >> 4) * 8;
    f32x4 acc1[4][2] = {}, acc2[4][2] = {};
    for (int s0 = 0; s0 < T; s0 += 32) {
        *(uint4*)&A1[sr*40 + sc]      = *(const uint4*)&Etb[(size_t)(d0+sr)*T + s0 + sc];
        *(uint4*)&A1[(sr+64)*40 + sc] = *(const uint4*)&Etb[(size_t)(d0+sr+64)*T + s0 + sc];
        *(uint4*)&A2[sr*40 + sc]      = *(const uint4*)&Ebb[(size_t)(d0+sr)*T + s0 + sc];
        *(uint4*)&A2[(sr+64)*40 + sc] = *(const uint4*)&Ebb[(size_t)(d0+sr+64)*T + s0 + sc];
        *(uint4*)&Bf[sr*40 + sc]      = *(const uint4*)&vfb[(size_t)(w0+sr)*T + s0 + sc];
        *(uint4*)&Bb[sr*40 + sc]      = *(const uint4*)&vbb[(size_t)(w0+sr)*T + s0 + sc];
        __syncthreads();
        bf16x8 a1[4], a2[4], bfv[2], bbv[2];
        #pragma unroll
        for (int i = 0; i < 4; ++i) {
            a1[i] = *(const bf16x8*)&A1[(wm*64 + i*16 + fr)*40 + fg];
            a2[i] = *(const bf16x8*)&A2[(wm*64 + i*16 + fr)*40 + fg];
        }
        #pragma unroll
        for (int i = 0; i < 2; ++i) {
            bfv[i] = *(const bf16x8*)&Bf[(wn*32 + i*16 + fr)*40 + fg];
            bbv[i] = *(const bf16x8*)&Bb[(wn*32 + i*16 + fr)*40 + fg];
        }
        #pragma unroll
        for (int mi = 0; mi < 4; ++mi)
            #pragma unroll
            for (int ni = 0; ni < 2; ++ni) {
                acc1[mi][ni] = __builtin_amdgcn_mfma_f32_16x16x32_bf16(a1[mi], bfv[ni], acc1[mi][ni], 0, 0, 0);
                acc2[mi][ni] = __builtin_amdgcn_mfma_f32_16x16x32_bf16(a2[mi], bbv[ni], acc2[mi][ni], 0, 0, 0);
            }
        __syncthreads();
    }
    int fq = lane >> 4;
    float* pb = part + (size_t)bh*T*D;
    #pragma unroll
    for (int mi = 0; mi < 4; ++mi)
        #pragma unroll
        for (int r = 0; r < 4; ++r) {
            int d = d0 + wm*64 + mi*16 + fq*4 + r;
            float ic = 1.f / csum[bh*T + d];
            float ir = 1.f / rsum[bh*T + d];
            #pragma unroll
            for (int ni = 0; ni < 2; ++ni) {
                int w = w0 + wn*32 + ni*16 + fr;
                pb[(size_t)d*D + w] = acc1[mi][ni][r]*ic + acc2[mi][ni][r]*ir;
            }
        }
}

// ---- K4b: head-reduce + SiLU ----------------------------------------------
__global__ __launch_bounds__(256) void k4b_reduce_silu(const float* __restrict__ part,
        float* __restrict__ z) {
    int idx = blockIdx.x * 256 + threadIdx.x;
    int b_ = idx >> 17;
    int td = idx & 131071;
    float s = 0.f;
    #pragma unroll
    for (int h = 0; h < H; ++h)
        s += part[(size_t)(b_*H + h) * T * D + td];
    z[idx] = s / (1.f + __expf(-1.702f * s));
}

// ---- K5: out = x + z @ fanin_w^T + fanin_b (fp32, small) -------------------
__global__ __launch_bounds__(256) void k5_fanin(const float* __restrict__ z,
        const float* __restrict__ fw, const float* __restrict__ fb,
        const float* __restrict__ x, float* __restrict__ out) {
    __shared__ float As[64][33];
    __shared__ float Bs[32][68];
    int bm = blockIdx.x * 64;
    int bn = blockIdx.y * 64;
    int tid = threadIdx.x;
    int tx = tid & 15, ty = tid >> 4;
    float acc[4][4] = {};
    for (int k0 = 0; k0 < 256; k0 += 32) {
        int r = tid >> 3, c4 = (tid & 7) * 4;
        for (int rr = r; rr < 64; rr += 32) {
            float4 v = *(const float4*)&z[(size_t)(bm + rr) * 256 + k0 + c4];
            As[rr][c4+0]=v.x; As[rr][c4+1]=v.y; As[rr][c4+2]=v.z; As[rr][c4+3]=v.w;
        }
        for (int nn = r; nn < 64; nn += 32) {
            float4 v = *(const float4*)&fw[(size_t)(bn + nn) * 256 + k0 + c4];
            Bs[c4+0][nn]=v.x; Bs[c4+1][nn]=v.y; Bs[c4+2][nn]=v.z; Bs[c4+3][nn]=v.w;
        }
        __syncthreads();
        for (int kk = 0; kk < 32; ++kk) {
            float a[4];
            #pragma unroll
            for (int i=0;i<4;++i) a[i] = As[ty*4+i][kk];
            float4 bv = *(const float4*)&Bs[kk][tx*4];
            #pragma unroll
            for (int i=0;i<4;++i) {
                acc[i][0] += a[i]*bv.x; acc[i][1] += a[i]*bv.y;
                acc[i][2] += a[i]*bv.z; acc[i][3] += a[i]*bv.w;
            }
        }
        __syncthreads();
    }
    #pragma unroll
    for (int i=0;i<4;++i) {
        int m = bm + ty*4 + i;
        int n = bn + tx*4;
        float4 xv = *(const float4*)&x[(size_t)m*256 + n];
        float4 v;
        v.x = acc[i][0] + fb[n+0] + xv.x;
        v.y = acc[i][1] + fb[n+1] + xv.y;
        v.z = acc[i][2] + fb[n+2] + xv.z;
        v.w = acc[i][3] + fb[n+3] + xv.w;
        *(float4*)&out[(size_t)m*256 + n] = v;
    }
}

extern "C" void kernel_launch(void* const* d_in, const int* in_sizes, int n_in,
                              void* d_out, int out_size, void* d_ws, size_t ws_size,
                              hipStream_t stream) {
    const float* x       = (const float*)d_in[0];
    const float* wk      = (const float*)d_in[1];
    const float* wqv_w   = (const float*)d_in[2];
    const float* wqv_b   = (const float*)d_in[3];
    const float* fanin_w = (const float*)d_in[4];
    const float* fanin_b = (const float*)d_in[5];
    char* wsb = (char*)d_ws;
    ushort* xb   = (ushort*)(wsb);                 // 1,048,576 B (bf16 x)
    ushort* wqvb = (ushort*)(wsb + 1048576);       // 3,145,728  (bf16 wqv)
    ushort* qTb  = (ushort*)(wsb + 4194304);       // 8,388,608  q f16 [bh][w][t]
    ushort* vfT  = (ushort*)(wsb + 12582912);      // 8,388,608  bf16 [bh][w][t]
    ushort* vbT  = (ushort*)(wsb + 20971520);      // 8,388,608
    ushort* Eb   = (ushort*)(wsb + 29360128);      // 16,777,216 bf16 [bh][s][d]
    ushort* Etb  = (ushort*)(wsb + 46137344);      // 16,777,216 bf16 [bh][d][s]
    float*  rsum = (float*)(wsb + 62914560);       // 65,536 (rsum+csum contiguous)
    float*  csum = (float*)(wsb + 62980096);       // 65,536
    float*  part = (float*)(wsb + 63045632);       // 16,777,216 (written by k4)
    // live only k0..k2, overlapped inside the (later-written) part region:
    ushort* xh   = (ushort*)(wsb + 63045632);      // 1,048,576  f16 x
    ushort* wkh  = (ushort*)(wsb + 64094208);      // 4,096      f16 wk
    float*  Qsum = (float*)(wsb + 64098304);       // 65,536
    float*  Ksum = (float*)(wsb + 64163840);       // 65,536
    float*  z    = (float*)(wsb + 79822848);       // 2,097,152
    float* out   = (float*)d_out;

    k0_convert     <<<2050, 256, 0, stream>>>(x, wqv_w, wk, xb, xh, wqvb, (ushort*)wkh, rsum, Qsum);
    k2a_sums       <<<4096, 256, 0, stream>>>(xh, (const uint*)wkh, Ksum);
    k1_qkv         <<<dim3(16, 48), 256, 0, stream>>>(xb, wqvb, wqv_b, qTb, vfT, vbT, Qsum);
    k2_scores      <<<dim3(4, 8, 32), 256, 0, stream>>>(qTb, xh, (const uint*)wkh, Qsum, Ksum, Eb, Etb, rsum, csum);
    k4_attn        <<<dim3(4, 4, 32), 256, 0, stream>>>(Eb, Etb, vfT, vbT, rsum, csum, part);
    k4b_reduce_silu<<<2048, 256, 0, stream>>>(part, z);
    k5_fanin       <<<dim3(32, 4), 256, 0, stream>>>(z, fanin_w, fanin_b, x, out);
}

// Round 8
// 237.179 us; speedup vs baseline: 1.0132x; 1.0132x over previous
//
#include <hip/hip_runtime.h>
#include <hip/hip_bf16.h>
#include <math.h>

#define B 4
#define T 512
#define D 256
#define H 8
#define BH (B*H)
#define SCALE 0.0625f

typedef float f32x4 __attribute__((ext_vector_type(4)));
typedef short bf16x8 __attribute__((ext_vector_type(8)));
typedef _Float16 f16x2 __attribute__((ext_vector_type(2)));

__device__ __forceinline__ ushort f2b(float f) {
    __hip_bfloat16 h = __float2bfloat16(f);
    return *reinterpret_cast<ushort*>(&h);
}
__device__ __forceinline__ float b2f(ushort u) {
    __hip_bfloat16 h;
    *reinterpret_cast<ushort*>(&h) = u;
    return __bfloat162float(h);
}
__device__ __forceinline__ ushort f2h(float f) {
    _Float16 h = (_Float16)f;
    ushort u; __builtin_memcpy(&u, &h, 2); return u;
}
// single-instruction packed-f16 ops (one inst per asm so scheduler interleaves)
__device__ __forceinline__ uint hmax2u(uint a, uint b) {
    uint d; asm("v_pk_max_f16 %0, %1, %2" : "=v"(d) : "v"(a), "v"(b)); return d;
}
__device__ __forceinline__ uint hadd2u(uint a, uint b) {
    uint d; asm("v_pk_add_f16 %0, %1, %2" : "=v"(d) : "v"(a), "v"(b)); return d;
}
__device__ __forceinline__ uint hmul2u(uint a, uint b) {
    uint d; asm("v_pk_mul_f16 %0, %1, %2" : "=v"(d) : "v"(a), "v"(b)); return d;
}
__device__ __forceinline__ float h2lo(uint u) {
    f16x2 t = __builtin_bit_cast(f16x2, u); return (float)t[0];
}
__device__ __forceinline__ float h2hi(uint u) {
    f16x2 t = __builtin_bit_cast(f16x2, u); return (float)t[1];
}

// ---- K0: x -> bf16 + f16; wqv_w -> bf16; wk -> f16; zero Qsum/rsum/csum/zacc
__global__ __launch_bounds__(256) void k0_convert(const float* __restrict__ x,
        const float* __restrict__ w, const float* __restrict__ wk,
        ushort* __restrict__ xb, ushort* __restrict__ xh,
        ushort* __restrict__ wb, ushort* __restrict__ wkh,
        float* __restrict__ rszero, float* __restrict__ Qsum,
        float* __restrict__ zacc) {
    int bx = blockIdx.x;
    if (bx < 32) {          // zero rsum+csum (32768 floats)
        ((float4*)rszero)[bx*256 + threadIdx.x] = make_float4(0.f,0.f,0.f,0.f);
    } else if (bx < 48) {   // zero Qsum (16384 floats)
        ((float4*)Qsum)[(bx-32)*256 + threadIdx.x] = make_float4(0.f,0.f,0.f,0.f);
    } else if (bx < 560) {  // zero zacc (524288 floats)
        ((float4*)zacc)[(bx-48)*256 + threadIdx.x] = make_float4(0.f,0.f,0.f,0.f);
    }
    int i = bx * 256 + threadIdx.x;
    if (i < 131072) {
        float4 v = ((const float4*)x)[i];
        ((ushort4*)xb)[i] = make_ushort4(f2b(v.x), f2b(v.y), f2b(v.z), f2b(v.w));
        ((ushort4*)xh)[i] = make_ushort4(f2h(v.x), f2h(v.y), f2h(v.z), f2h(v.w));
    } else if (i < 524288) {
        int j = i - 131072;
        float4 v = ((const float4*)w)[j];
        ((ushort4*)wb)[j] = make_ushort4(f2b(v.x), f2b(v.y), f2b(v.z), f2b(v.w));
    } else if (i < 524288 + 512) {
        int j = i - 524288;
        float4 v = ((const float4*)wk)[j];
        ((ushort4*)wkh)[j] = make_ushort4(f2h(v.x), f2h(v.y), f2h(v.z), f2h(v.w));
    }
}

// ---- K2a: Ksum[bh][d] = sum_w f16(xh*wkh) (f16-consistent with k2 inner) ---
__global__ __launch_bounds__(256) void k2a_sums(const ushort* __restrict__ xh,
        const uint* __restrict__ wkh, float* __restrict__ Ksum) {
    int row = blockIdx.x * 4 + (threadIdx.x >> 6);   // 0..16383 = bh*512 + d
    int lane = threadIdx.x & 63;
    int b_ = row >> 12, h_ = (row >> 9) & 7, d_ = row & 511;
    uint2 xu = *(const uint2*)&xh[((size_t)(b_*T + d_))*D + lane*4];
    uint2 wv = *(const uint2*)&wkh[h_*128 + lane*2];
    uint p0 = hmul2u(xu.x, wv.x);
    uint p1 = hmul2u(xu.y, wv.y);
    float s = h2lo(p0) + h2hi(p0) + h2lo(p1) + h2hi(p1);
    #pragma unroll
    for (int o = 32; o > 0; o >>= 1) s += __shfl_xor(s, o);
    if (lane == 0) Ksum[row] = s;
}

// ---- K1: bf16 MFMA GEMM  v = x @ wqv^T + bias ------------------------------
// ALL outputs via LDS transpose: q(f16) [bh][w][t], vf/vb(bf16) [bh][w][t].
// Qsum[bh][t] = sum_w q fused via shfl+atomics.
__global__ __launch_bounds__(256) void k1_qkv(const ushort* __restrict__ xb,
        const ushort* __restrict__ wb, const float* __restrict__ bias,
        ushort* __restrict__ qT, ushort* __restrict__ vf, ushort* __restrict__ vb,
        float* __restrict__ Qsum) {
    __shared__ ushort AB[2*128*40];
    ushort* As = AB;
    ushort* Bs = AB + 128*40;
    int tid = threadIdx.x;
    int lane = tid & 63, wave = tid >> 6;
    int wm = wave >> 1, wn = wave & 1;
    int bm0 = blockIdx.x * 128, bn0 = blockIdx.y * 128;
    f32x4 acc[4][4] = {};
    int sr = tid >> 2, sc = (tid & 3) * 8;
    int fr = lane & 15, fg = (lane >> 4) * 8;
    for (int k0 = 0; k0 < 256; k0 += 32) {
        *(uint4*)&As[sr*40 + sc]      = *(const uint4*)&xb[(size_t)(bm0+sr)*256 + k0 + sc];
        *(uint4*)&As[(sr+64)*40 + sc] = *(const uint4*)&xb[(size_t)(bm0+sr+64)*256 + k0 + sc];
        *(uint4*)&Bs[sr*40 + sc]      = *(const uint4*)&wb[(size_t)(bn0+sr)*256 + k0 + sc];
        *(uint4*)&Bs[(sr+64)*40 + sc] = *(const uint4*)&wb[(size_t)(bn0+sr+64)*256 + k0 + sc];
        __syncthreads();
        bf16x8 af[4], bfv[4];
        #pragma unroll
        for (int i = 0; i < 4; ++i)
            af[i] = *(const bf16x8*)&As[(wm*64 + i*16 + fr)*40 + fg];
        #pragma unroll
        for (int i = 0; i < 4; ++i)
            bfv[i] = *(const bf16x8*)&Bs[(wn*64 + i*16 + fr)*40 + fg];
        #pragma unroll
        for (int mi = 0; mi < 4; ++mi)
            #pragma unroll
            for (int ni = 0; ni < 4; ++ni)
                acc[mi][ni] = __builtin_amdgcn_mfma_f32_16x16x32_bf16(af[mi], bfv[ni], acc[mi][ni], 0, 0, 0);
        __syncthreads();
    }
    int fq = lane >> 4;
    int g = bn0 >> 11;
    int b_ = bm0 >> 9;
    int t0base = bm0 & 511;
    float bn_[4];
    #pragma unroll
    for (int ni = 0; ni < 4; ++ni) bn_[ni] = bias[bn0 + wn*64 + ni*16 + fr];

    if (g == 0) {   // Qsum partials: t fixed across fr-lanes
        int h_ = bn0 >> 8;
        #pragma unroll
        for (int mi = 0; mi < 4; ++mi)
            #pragma unroll
            for (int r = 0; r < 4; ++r) {
                float v = (acc[mi][0][r]+bn_[0]) + (acc[mi][1][r]+bn_[1])
                        + (acc[mi][2][r]+bn_[2]) + (acc[mi][3][r]+bn_[3]);
                v += __shfl_xor(v, 1); v += __shfl_xor(v, 2);
                v += __shfl_xor(v, 4); v += __shfl_xor(v, 8);
                if (fr == 0)
                    atomicAdd(&Qsum[(b_*H + h_)*T + t0base + wm*64 + mi*16 + fq*4 + r], v);
            }
    }
    // transpose epilogue: tb = [64 n-half][132 m]
    ushort* dstbase = (g == 0) ? qT : (g == 1 ? vf : vb);
    ushort* tb = AB;
    #pragma unroll
    for (int hf = 0; hf < 2; ++hf) {
        __syncthreads();
        if (wn == hf) {
            #pragma unroll
            for (int ni = 0; ni < 4; ++ni) {
                int nh = ni*16 + fr;
                #pragma unroll
                for (int mi = 0; mi < 4; ++mi) {
                    int mloc = wm*64 + mi*16 + fq*4;
                    float v0 = acc[mi][ni][0] + bn_[ni];
                    float v1 = acc[mi][ni][1] + bn_[ni];
                    float v2 = acc[mi][ni][2] + bn_[ni];
                    float v3 = acc[mi][ni][3] + bn_[ni];
                    *(ushort4*)&tb[nh*132 + mloc] = (g == 0)
                        ? make_ushort4(f2h(v0), f2h(v1), f2h(v2), f2h(v3))
                        : make_ushort4(f2b(v0), f2b(v1), f2b(v2), f2b(v3));
                }
            }
        }
        __syncthreads();
        #pragma unroll
        for (int p = 0; p < 2; ++p) {
            int rr = tid >> 2;
            int cc = (tid & 3)*16 + p*64;
            const ushort* src = &tb[rr*132 + cc];
            uint2 a0 = *(const uint2*)(src);
            uint2 a1 = *(const uint2*)(src + 4);
            uint2 a2 = *(const uint2*)(src + 8);
            uint2 a3 = *(const uint2*)(src + 12);
            int n = bn0 + hf*64 + rr;
            int h_ = (n & 2047) >> 8, w_ = n & 255;
            ushort* dst = dstbase + ((size_t)(b_*H + h_)*D + w_)*T + t0base + cc;
            *(uint4*)dst       = make_uint4(a0.x, a0.y, a1.x, a1.y);
            *(uint4*)(dst + 8) = make_uint4(a2.x, a2.y, a3.x, a3.y);
        }
    }
}

// ---- K2: E = exp(-SCALE*(2*sum max(q,k) - Qsum - Ksum)); E, Et, rsum, csum -
// 128x128 tile, 8x8/thread (2x arith intensity of 128x64). Direct E/Et stores
// (L2 merges: round-4 WRITE_SIZE == exactly E+Et). Grid (4,4,32)=512 blocks.
__global__ __launch_bounds__(256, 2) void k2_scores(const ushort* __restrict__ qT,
        const ushort* __restrict__ xh, const uint* __restrict__ wkh,
        const float* __restrict__ Qsum, const float* __restrict__ Ksum,
        ushort* __restrict__ E, ushort* __restrict__ Et,
        float* __restrict__ rsum, float* __restrict__ csum) {
    __shared__ uint Qs[32*132];   // [up][128 t + pad]
    __shared__ uint Ks[32*132];   // [up][128 d + pad]
    __shared__ float cspart[128];
    int s0 = blockIdx.x*128, d0 = blockIdx.y*128, bh = blockIdx.z;
    int b_ = bh>>3, h_ = bh&7;
    int tid = threadIdx.x, tx = tid&15, ty = tid>>4;
    const ushort* qbb = qT + (size_t)bh*D*T;
    const ushort* xbb = xh + (size_t)b_*T*D;
    if (tid < 128) cspart[tid] = 0.f;
    int rp = tid>>3, tc = (tid&7)*16;   // Q staging: w-pair row, t-chunk
    int dr = tid>>1, cw = (tid&1)*32;   // K staging: d-row, 32-w chunk
    float accf[8][8] = {};
    for (int c = 0; c < 4; ++c) {
        int w0 = c*64;
        if (c) __syncthreads();
        {   // Q stage: rows (w0+2rp, +1) from [bh][w][t], pair-pack along w
            const ushort* qr = &qbb[(size_t)(w0+2*rp)*T + s0 + tc];
            uint4 a0 = *(const uint4*)qr,     a1 = *(const uint4*)(qr+8);
            uint4 b0 = *(const uint4*)(qr+T), b1 = *(const uint4*)(qr+T+8);
            uint av[8] = {a0.x,a0.y,a0.z,a0.w,a1.x,a1.y,a1.z,a1.w};
            uint bv[8] = {b0.x,b0.y,b0.z,b0.w,b1.x,b1.y,b1.z,b1.w};
            uint o[16];
            #pragma unroll
            for (int j = 0; j < 8; ++j) {
                o[2*j]   = __builtin_amdgcn_perm(bv[j], av[j], 0x05040100u);
                o[2*j+1] = __builtin_amdgcn_perm(bv[j], av[j], 0x07060302u);
            }
            uint* qd = &Qs[rp*132 + tc];
            *(uint4*)(qd)    = make_uint4(o[0],o[1],o[2],o[3]);
            *(uint4*)(qd+4)  = make_uint4(o[4],o[5],o[6],o[7]);
            *(uint4*)(qd+8)  = make_uint4(o[8],o[9],o[10],o[11]);
            *(uint4*)(qd+12) = make_uint4(o[12],o[13],o[14],o[15]);
        }
        {   // K stage: k = f16(x*wk); x rows are w-contiguous -> natural pairs
            const ushort* xr = &xbb[(size_t)(d0+dr)*D + w0 + cw];
            uint4 x0 = *(const uint4*)xr,      x1 = *(const uint4*)(xr+8);
            uint4 x2 = *(const uint4*)(xr+16), x3 = *(const uint4*)(xr+24);
            const uint* wp = &wkh[h_*128 + ((w0+cw)>>1)];
            uint4 w0v = *(const uint4*)wp,     w1v = *(const uint4*)(wp+4);
            uint4 w2v = *(const uint4*)(wp+8), w3v = *(const uint4*)(wp+12);
            uint xs[16] = {x0.x,x0.y,x0.z,x0.w, x1.x,x1.y,x1.z,x1.w,
                           x2.x,x2.y,x2.z,x2.w, x3.x,x3.y,x3.z,x3.w};
            uint ws[16] = {w0v.x,w0v.y,w0v.z,w0v.w, w1v.x,w1v.y,w1v.z,w1v.w,
                           w2v.x,w2v.y,w2v.z,w2v.w, w3v.x,w3v.y,w3v.z,w3v.w};
            int u0 = cw>>1;
            #pragma unroll
            for (int j = 0; j < 16; ++j)
                Ks[(u0+j)*132 + dr] = hmul2u(xs[j], ws[j]);
        }
        __syncthreads();
        uint acc2[8][8];
        #pragma unroll
        for (int i = 0; i < 8; ++i)
            #pragma unroll
            for (int j = 0; j < 8; ++j) acc2[i][j] = 0u;
        #pragma unroll 2
        for (int up = 0; up < 32; ++up) {
            const uint* qp = &Qs[up*132 + ty*8];
            uint4 qA = *(const uint4*)qp, qB = *(const uint4*)(qp+4);
            const uint* kp = &Ks[up*132 + tx*8];
            uint4 kA = *(const uint4*)kp, kB = *(const uint4*)(kp+4);
            uint q8[8] = {qA.x,qA.y,qA.z,qA.w, qB.x,qB.y,qB.z,qB.w};
            uint k8[8] = {kA.x,kA.y,kA.z,kA.w, kB.x,kB.y,kB.z,kB.w};
            #pragma unroll
            for (int i = 0; i < 8; ++i)
                #pragma unroll
                for (int j = 0; j < 8; ++j)
                    acc2[i][j] = hadd2u(acc2[i][j], hmax2u(q8[i], k8[j]));
        }
        #pragma unroll
        for (int i = 0; i < 8; ++i)
            #pragma unroll
            for (int j = 0; j < 8; ++j)
                accf[i][j] += h2lo(acc2[i][j]) + h2hi(acc2[i][j]);
    }
    // ---- epilogue: e = exp(-SCALE*(2M - Qsum - Ksum)) ----
    float qs8[8], ks8[8];
    {
        float4 qlo = *(const float4*)&Qsum[bh*T + s0 + ty*8];
        float4 qhi = *(const float4*)&Qsum[bh*T + s0 + ty*8 + 4];
        qs8[0]=qlo.x; qs8[1]=qlo.y; qs8[2]=qlo.z; qs8[3]=qlo.w;
        qs8[4]=qhi.x; qs8[5]=qhi.y; qs8[6]=qhi.z; qs8[7]=qhi.w;
        float4 klo = *(const float4*)&Ksum[bh*T + d0 + tx*8];
        float4 khi = *(const float4*)&Ksum[bh*T + d0 + tx*8 + 4];
        ks8[0]=klo.x; ks8[1]=klo.y; ks8[2]=klo.z; ks8[3]=klo.w;
        ks8[4]=khi.x; ks8[5]=khi.y; ks8[6]=khi.z; ks8[7]=khi.w;
    }
    #pragma unroll
    for (int i = 0; i < 8; ++i)
        #pragma unroll
        for (int j = 0; j < 8; ++j)
            accf[i][j] = __expf(-SCALE * (2.f*accf[i][j] - qs8[i] - ks8[j]));
    // E stores (row-major, 16 lanes x 16B = 256B segments)
    #pragma unroll
    for (int i = 0; i < 8; ++i) {
        ushort* ep = &E[((size_t)bh*T + s0 + ty*8 + i)*T + d0 + tx*8];
        *(ushort4*)ep     = make_ushort4(f2b(accf[i][0]), f2b(accf[i][1]), f2b(accf[i][2]), f2b(accf[i][3]));
        *(ushort4*)(ep+4) = make_ushort4(f2b(accf[i][4]), f2b(accf[i][5]), f2b(accf[i][6]), f2b(accf[i][7]));
    }
    // Et stores (direct; L2 merges the 4-ty 16B pieces per row)
    #pragma unroll
    for (int j = 0; j < 8; ++j) {
        ushort* tp = &Et[((size_t)bh*T + d0 + tx*8 + j)*T + s0 + ty*8];
        *(ushort4*)tp     = make_ushort4(f2b(accf[0][j]), f2b(accf[1][j]), f2b(accf[2][j]), f2b(accf[3][j]));
        *(ushort4*)(tp+4) = make_ushort4(f2b(accf[4][j]), f2b(accf[5][j]), f2b(accf[6][j]), f2b(accf[7][j]));
    }
    // rsum: reduce over j then across tx (16-lane groups) + atomic
    #pragma unroll
    for (int i = 0; i < 8; ++i) {
        float rs = accf[i][0]+accf[i][1]+accf[i][2]+accf[i][3]
                 + accf[i][4]+accf[i][5]+accf[i][6]+accf[i][7];
        rs += __shfl_xor(rs, 1); rs += __shfl_xor(rs, 2);
        rs += __shfl_xor(rs, 4); rs += __shfl_xor(rs, 8);
        if ((tid & 15) == 0) atomicAdd(&rsum[bh*T + s0 + ty*8 + i], rs);
    }
    // csum partials into LDS then global
    #pragma unroll
    for (int j = 0; j < 8; ++j) {
        float cs = 0.f;
        #pragma unroll
        for (int i = 0; i < 8; ++i) cs += accf[i][j];
        atomicAdd(&cspart[tx*8 + j], cs);
    }
    __syncthreads();
    if (tid < 128) atomicAdd(&csum[bh*T + d0 + tid], cspart[tid]);
}

// ---- K4: dual bf16 MFMA GEMM; epilogue atomicAdds head-sum into zacc -------
__global__ __launch_bounds__(256) void k4_attn(const ushort* __restrict__ E,
        const ushort* __restrict__ Et, const ushort* __restrict__ vfT,
        const ushort* __restrict__ vbT, const float* __restrict__ rsum,
        const float* __restrict__ csum, float* __restrict__ zacc) {
    __shared__ ushort A1[128*40];
    __shared__ ushort A2[128*40];
    __shared__ ushort Bf[64*40];
    __shared__ ushort Bb[64*40];
    int d0 = blockIdx.x * 128, w0 = blockIdx.y * 64, bh = blockIdx.z;
    const ushort* Ebb = E  + (size_t)bh*T*T;
    const ushort* Etb = Et + (size_t)bh*T*T;
    const ushort* vfb = vfT + (size_t)bh*D*T;
    const ushort* vbb = vbT + (size_t)bh*D*T;
    int tid = threadIdx.x, lane = tid & 63, wave = tid >> 6;
    int wm = wave >> 1, wn = wave & 1;
    int sr = tid >> 2, sc = (tid & 3) * 8;
    int fr = lane & 15, fg = (lane >> 4) * 8;
    f32x4 acc1[4][2] = {}, acc2[4][2] = {};
    for (int s0 = 0; s0 < T; s0 += 32) {
        *(uint4*)&A1[sr*40 + sc]      = *(const uint4*)&Etb[(size_t)(d0+sr)*T + s0 + sc];
        *(uint4*)&A1[(sr+64)*40 + sc] = *(const uint4*)&Etb[(size_t)(d0+sr+64)*T + s0 + sc];
        *(uint4*)&A2[sr*40 + sc]      = *(const uint4*)&Ebb[(size_t)(d0+sr)*T + s0 + sc];
        *(uint4*)&A2[(sr+64)*40 + sc] = *(const uint4*)&Ebb[(size_t)(d0+sr+64)*T + s0 + sc];
        *(uint4*)&Bf[sr*40 + sc]      = *(const uint4*)&vfb[(size_t)(w0+sr)*T + s0 + sc];
        *(uint4*)&Bb[sr*40 + sc]      = *(const uint4*)&vbb[(size_t)(w0+sr)*T + s0 + sc];
        __syncthreads();
        bf16x8 a1[4], a2[4], bfv[2], bbv[2];
        #pragma unroll
        for (int i = 0; i < 4; ++i) {
            a1[i] = *(const bf16x8*)&A1[(wm*64 + i*16 + fr)*40 + fg];
            a2[i] = *(const bf16x8*)&A2[(wm*64 + i*16 + fr)*40 + fg];
        }
        #pragma unroll
        for (int i = 0; i < 2; ++i) {
            bfv[i] = *(const bf16x8*)&Bf[(wn*32 + i*16 + fr)*40 + fg];
            bbv[i] = *(const bf16x8*)&Bb[(wn*32 + i*16 + fr)*40 + fg];
        }
        #pragma unroll
        for (int mi = 0; mi < 4; ++mi)
            #pragma unroll
            for (int ni = 0; ni < 2; ++ni) {
                acc1[mi][ni] = __builtin_amdgcn_mfma_f32_16x16x32_bf16(a1[mi], bfv[ni], acc1[mi][ni], 0, 0, 0);
                acc2[mi][ni] = __builtin_amdgcn_mfma_f32_16x16x32_bf16(a2[mi], bbv[ni], acc2[mi][ni], 0, 0, 0);
            }
        __syncthreads();
    }
    int fq = lane >> 4;
    float* zb = zacc + (size_t)(bh >> 3) * T * D;
    #pragma unroll
    for (int mi = 0; mi < 4; ++mi)
        #pragma unroll
        for (int r = 0; r < 4; ++r) {
            int d = d0 + wm*64 + mi*16 + fq*4 + r;
            float ic = 1.f / csum[bh*T + d];
            float ir = 1.f / rsum[bh*T + d];
            #pragma unroll
            for (int ni = 0; ni < 2; ++ni) {
                int w = w0 + wn*32 + ni*16 + fr;
                atomicAdd(&zb[(size_t)d*D + w], acc1[mi][ni][r]*ic + acc2[mi][ni][r]*ir);
            }
        }
}

// ---- K5: out = x + silu(zacc) @ fanin_w^T + fanin_b ------------------------
__global__ __launch_bounds__(256) void k5_fanin(const float* __restrict__ zacc,
        const float* __restrict__ fw, const float* __restrict__ fb,
        const float* __restrict__ x, float* __restrict__ out) {
    __shared__ float As[64][33];
    __shared__ float Bs[32][68];
    int bm = blockIdx.x * 64;
    int bn = blockIdx.y * 64;
    int tid = threadIdx.x;
    int tx = tid & 15, ty = tid >> 4;
    float acc[4][4] = {};
    for (int k0 = 0; k0 < 256; k0 += 32) {
        int r = tid >> 3, c4 = (tid & 7) * 4;
        for (int rr = r; rr < 64; rr += 32) {
            float4 v = *(const float4*)&zacc[(size_t)(bm + rr) * 256 + k0 + c4];
            As[rr][c4+0] = v.x / (1.f + __expf(-1.702f*v.x));
            As[rr][c4+1] = v.y / (1.f + __expf(-1.702f*v.y));
            As[rr][c4+2] = v.z / (1.f + __expf(-1.702f*v.z));
            As[rr][c4+3] = v.w / (1.f + __expf(-1.702f*v.w));
        }
        for (int nn = r; nn < 64; nn += 32) {
            float4 v = *(const float4*)&fw[(size_t)(bn + nn) * 256 + k0 + c4];
            Bs[c4+0][nn]=v.x; Bs[c4+1][nn]=v.y; Bs[c4+2][nn]=v.z; Bs[c4+3][nn]=v.w;
        }
        __syncthreads();
        for (int kk = 0; kk < 32; ++kk) {
            float a[4];
            #pragma unroll
            for (int i=0;i<4;++i) a[i] = As[ty*4+i][kk];
            float4 bv = *(const float4*)&Bs[kk][tx*4];
            #pragma unroll
            for (int i=0;i<4;++i) {
                acc[i][0] += a[i]*bv.x; acc[i][1] += a[i]*bv.y;
                acc[i][2] += a[i]*bv.z; acc[i][3] += a[i]*bv.w;
            }
        }
        __syncthreads();
    }
    #pragma unroll
    for (int i=0;i<4;++i) {
        int m = bm + ty*4 + i;
        int n = bn + tx*4;
        float4 xv = *(const float4*)&x[(size_t)m*256 + n];
        float4 v;
        v.x = acc[i][0] + fb[n+0] + xv.x;
        v.y = acc[i][1] + fb[n+1] + xv.y;
        v.z = acc[i][2] + fb[n+2] + xv.z;
        v.w = acc[i][3] + fb[n+3] + xv.w;
        *(float4*)&out[(size_t)m*256 + n] = v;
    }
}

extern "C" void kernel_launch(void* const* d_in, const int* in_sizes, int n_in,
                              void* d_out, int out_size, void* d_ws, size_t ws_size,
                              hipStream_t stream) {
    const float* x       = (const float*)d_in[0];
    const float* wk      = (const float*)d_in[1];
    const float* wqv_w   = (const float*)d_in[2];
    const float* wqv_b   = (const float*)d_in[3];
    const float* fanin_w = (const float*)d_in[4];
    const float* fanin_b = (const float*)d_in[5];
    char* wsb = (char*)d_ws;
    ushort* xb   = (ushort*)(wsb);                 // 1,048,576 B (bf16 x)
    ushort* wqvb = (ushort*)(wsb + 1048576);       // 3,145,728  (bf16 wqv)
    ushort* qTb  = (ushort*)(wsb + 4194304);       // 8,388,608  q f16 [bh][w][t]
    ushort* vfT  = (ushort*)(wsb + 12582912);      // 8,388,608  bf16 [bh][w][t]
    ushort* vbT  = (ushort*)(wsb + 20971520);      // 8,388,608
    ushort* Eb   = (ushort*)(wsb + 29360128);      // 16,777,216 bf16 [bh][s][d]
    ushort* Etb  = (ushort*)(wsb + 46137344);      // 16,777,216 bf16 [bh][d][s]
    float*  rsum = (float*)(wsb + 62914560);       // 65,536 (rsum+csum contiguous)
    float*  csum = (float*)(wsb + 62980096);       // 65,536
    ushort* xh   = (ushort*)(wsb + 63045632);      // 1,048,576  f16 x
    ushort* wkh  = (ushort*)(wsb + 64094208);      // 4,096      f16 wk
    float*  Qsum = (float*)(wsb + 64098304);       // 65,536
    float*  Ksum = (float*)(wsb + 64163840);       // 65,536
    float*  zacc = (float*)(wsb + 79822848);       // 2,097,152  head-summed bo
    float* out   = (float*)d_out;

    k0_convert     <<<2050, 256, 0, stream>>>(x, wqv_w, wk, xb, xh, wqvb, (ushort*)wkh, rsum, Qsum, zacc);
    k2a_sums       <<<4096, 256, 0, stream>>>(xh, (const uint*)wkh, Ksum);
    k1_qkv         <<<dim3(16, 48), 256, 0, stream>>>(xb, wqvb, wqv_b, qTb, vfT, vbT, Qsum);
    k2_scores      <<<dim3(4, 4, 32), 256, 0, stream>>>(qTb, xh, (const uint*)wkh, Qsum, Ksum, Eb, Etb, rsum, csum);
    k4_attn        <<<dim3(4, 4, 32), 256, 0, stream>>>(Eb, Etb, vfT, vbT, rsum, csum, zacc);
    k5_fanin       <<<dim3(32, 4), 256, 0, stream>>>(zacc, fanin_w, fanin_b, x, out);
}

// Round 9
// 234.974 us; speedup vs baseline: 1.0227x; 1.0094x over previous
//
#include <hip/hip_runtime.h>
#include <hip/hip_bf16.h>
#include <math.h>

#define B 4
#define T 512
#define D 256
#define H 8
#define BH (B*H)
#define SCALE 0.0625f

typedef float f32x4 __attribute__((ext_vector_type(4)));
typedef short bf16x8 __attribute__((ext_vector_type(8)));
typedef _Float16 f16x2 __attribute__((ext_vector_type(2)));

__device__ __forceinline__ ushort f2b(float f) {
    __hip_bfloat16 h = __float2bfloat16(f);
    return *reinterpret_cast<ushort*>(&h);
}
__device__ __forceinline__ float b2f(ushort u) {
    __hip_bfloat16 h;
    *reinterpret_cast<ushort*>(&h) = u;
    return __bfloat162float(h);
}
__device__ __forceinline__ ushort f2h(float f) {
    _Float16 h = (_Float16)f;
    ushort u; __builtin_memcpy(&u, &h, 2); return u;
}
// single-instruction packed-f16 ops (one inst per asm so scheduler interleaves)
__device__ __forceinline__ uint hmax2u(uint a, uint b) {
    uint d; asm("v_pk_max_f16 %0, %1, %2" : "=v"(d) : "v"(a), "v"(b)); return d;
}
__device__ __forceinline__ uint hadd2u(uint a, uint b) {
    uint d; asm("v_pk_add_f16 %0, %1, %2" : "=v"(d) : "v"(a), "v"(b)); return d;
}
__device__ __forceinline__ uint hmul2u(uint a, uint b) {
    uint d; asm("v_pk_mul_f16 %0, %1, %2" : "=v"(d) : "v"(a), "v"(b)); return d;
}
__device__ __forceinline__ float h2lo(uint u) {
    f16x2 t = __builtin_bit_cast(f16x2, u); return (float)t[0];
}
__device__ __forceinline__ float h2hi(uint u) {
    f16x2 t = __builtin_bit_cast(f16x2, u); return (float)t[1];
}

// ---- K0 (fused): conversions + zero-init + Ksum reduction ------------------
// blocks 0..2049: x->bf16+f16, wqv->bf16, wk->f16, zero Qsum/rsum/csum/zacc.
// blocks 2050..6145: Ksum[bh][d] = sum_w f16(x)*f16(wk)  (f16-identical to k2)
__global__ __launch_bounds__(256) void k0_fused(const float* __restrict__ x,
        const float* __restrict__ w, const float* __restrict__ wk,
        ushort* __restrict__ xb, ushort* __restrict__ xh,
        ushort* __restrict__ wb, ushort* __restrict__ wkh,
        float* __restrict__ rszero, float* __restrict__ Qsum,
        float* __restrict__ zacc, float* __restrict__ Ksum) {
    int bx = blockIdx.x;
    if (bx < 2050) {
        if (bx < 32) {          // zero rsum+csum (32768 floats)
            ((float4*)rszero)[bx*256 + threadIdx.x] = make_float4(0.f,0.f,0.f,0.f);
        } else if (bx < 48) {   // zero Qsum (16384 floats)
            ((float4*)Qsum)[(bx-32)*256 + threadIdx.x] = make_float4(0.f,0.f,0.f,0.f);
        } else if (bx < 560) {  // zero zacc (524288 floats)
            ((float4*)zacc)[(bx-48)*256 + threadIdx.x] = make_float4(0.f,0.f,0.f,0.f);
        }
        int i = bx * 256 + threadIdx.x;
        if (i < 131072) {
            float4 v = ((const float4*)x)[i];
            ((ushort4*)xb)[i] = make_ushort4(f2b(v.x), f2b(v.y), f2b(v.z), f2b(v.w));
            ((ushort4*)xh)[i] = make_ushort4(f2h(v.x), f2h(v.y), f2h(v.z), f2h(v.w));
        } else if (i < 524288) {
            int j = i - 131072;
            float4 v = ((const float4*)w)[j];
            ((ushort4*)wb)[j] = make_ushort4(f2b(v.x), f2b(v.y), f2b(v.z), f2b(v.w));
        } else if (i < 524288 + 512) {
            int j = i - 524288;
            float4 v = ((const float4*)wk)[j];
            ((ushort4*)wkh)[j] = make_ushort4(f2h(v.x), f2h(v.y), f2h(v.z), f2h(v.w));
        }
    } else {
        int row = (bx - 2050) * 4 + (threadIdx.x >> 6);   // bh*512 + d
        int lane = threadIdx.x & 63;
        int b_ = row >> 12, h_ = (row >> 9) & 7, d_ = row & 511;
        float4 xv = *(const float4*)&x[((size_t)(b_*T + d_))*D + lane*4];
        float4 wv = *(const float4*)&wk[h_*D + lane*4];
        float s = (float)((_Float16)xv.x * (_Float16)wv.x)
                + (float)((_Float16)xv.y * (_Float16)wv.y)
                + (float)((_Float16)xv.z * (_Float16)wv.z)
                + (float)((_Float16)xv.w * (_Float16)wv.w);
        #pragma unroll
        for (int o = 32; o > 0; o >>= 1) s += __shfl_xor(s, o);
        if (lane == 0) Ksum[row] = s;
    }
}

// ---- K1: bf16 MFMA GEMM  v = x @ wqv^T + bias ------------------------------
// ALL outputs via LDS transpose: q(f16) [bh][w][t], vf/vb(bf16) [bh][w][t].
// Readout: 4 threads/row x 64B contiguous -> no write amplification.
__global__ __launch_bounds__(256) void k1_qkv(const ushort* __restrict__ xb,
        const ushort* __restrict__ wb, const float* __restrict__ bias,
        ushort* __restrict__ qT, ushort* __restrict__ vf, ushort* __restrict__ vb,
        float* __restrict__ Qsum) {
    __shared__ ushort AB[2*128*40];
    ushort* As = AB;
    ushort* Bs = AB + 128*40;
    int tid = threadIdx.x;
    int lane = tid & 63, wave = tid >> 6;
    int wm = wave >> 1, wn = wave & 1;
    int bm0 = blockIdx.x * 128, bn0 = blockIdx.y * 128;
    f32x4 acc[4][4] = {};
    int sr = tid >> 2, sc = (tid & 3) * 8;
    int fr = lane & 15, fg = (lane >> 4) * 8;
    for (int k0 = 0; k0 < 256; k0 += 32) {
        *(uint4*)&As[sr*40 + sc]      = *(const uint4*)&xb[(size_t)(bm0+sr)*256 + k0 + sc];
        *(uint4*)&As[(sr+64)*40 + sc] = *(const uint4*)&xb[(size_t)(bm0+sr+64)*256 + k0 + sc];
        *(uint4*)&Bs[sr*40 + sc]      = *(const uint4*)&wb[(size_t)(bn0+sr)*256 + k0 + sc];
        *(uint4*)&Bs[(sr+64)*40 + sc] = *(const uint4*)&wb[(size_t)(bn0+sr+64)*256 + k0 + sc];
        __syncthreads();
        bf16x8 af[4], bfv[4];
        #pragma unroll
        for (int i = 0; i < 4; ++i)
            af[i] = *(const bf16x8*)&As[(wm*64 + i*16 + fr)*40 + fg];
        #pragma unroll
        for (int i = 0; i < 4; ++i)
            bfv[i] = *(const bf16x8*)&Bs[(wn*64 + i*16 + fr)*40 + fg];
        #pragma unroll
        for (int mi = 0; mi < 4; ++mi)
            #pragma unroll
            for (int ni = 0; ni < 4; ++ni)
                acc[mi][ni] = __builtin_amdgcn_mfma_f32_16x16x32_bf16(af[mi], bfv[ni], acc[mi][ni], 0, 0, 0);
        __syncthreads();
    }
    int fq = lane >> 4;
    int g = bn0 >> 11;
    int b_ = bm0 >> 9;
    int t0base = bm0 & 511;
    float bn_[4];
    #pragma unroll
    for (int ni = 0; ni < 4; ++ni) bn_[ni] = bias[bn0 + wn*64 + ni*16 + fr];

    if (g == 0) {   // Qsum partials: t fixed across fr-lanes
        int h_ = bn0 >> 8;
        #pragma unroll
        for (int mi = 0; mi < 4; ++mi)
            #pragma unroll
            for (int r = 0; r < 4; ++r) {
                float v = (acc[mi][0][r]+bn_[0]) + (acc[mi][1][r]+bn_[1])
                        + (acc[mi][2][r]+bn_[2]) + (acc[mi][3][r]+bn_[3]);
                v += __shfl_xor(v, 1); v += __shfl_xor(v, 2);
                v += __shfl_xor(v, 4); v += __shfl_xor(v, 8);
                if (fr == 0)
                    atomicAdd(&Qsum[(b_*H + h_)*T + t0base + wm*64 + mi*16 + fq*4 + r], v);
            }
    }
    // transpose epilogue: tb = [64 n-half][132 m]
    ushort* dstbase = (g == 0) ? qT : (g == 1 ? vf : vb);
    ushort* tb = AB;
    #pragma unroll
    for (int hf = 0; hf < 2; ++hf) {
        __syncthreads();
        if (wn == hf) {
            #pragma unroll
            for (int ni = 0; ni < 4; ++ni) {
                int nh = ni*16 + fr;
                #pragma unroll
                for (int mi = 0; mi < 4; ++mi) {
                    int mloc = wm*64 + mi*16 + fq*4;
                    float v0 = acc[mi][ni][0] + bn_[ni];
                    float v1 = acc[mi][ni][1] + bn_[ni];
                    float v2 = acc[mi][ni][2] + bn_[ni];
                    float v3 = acc[mi][ni][3] + bn_[ni];
                    *(ushort4*)&tb[nh*132 + mloc] = (g == 0)
                        ? make_ushort4(f2h(v0), f2h(v1), f2h(v2), f2h(v3))
                        : make_ushort4(f2b(v0), f2b(v1), f2b(v2), f2b(v3));
                }
            }
        }
        __syncthreads();
        {   // 4 threads per n-row, 64B (32 m) contiguous each
            int rr = tid >> 2;                // 0..63
            int cc = (tid & 3) * 32;          // m offset
            const ushort* src = &tb[rr*132 + cc];
            uint4 a0 = *(const uint4*)(src);
            uint4 a1 = *(const uint4*)(src + 8);
            uint4 a2 = *(const uint4*)(src + 16);
            uint4 a3 = *(const uint4*)(src + 24);
            int n = bn0 + hf*64 + rr;
            int h_ = (n & 2047) >> 8, w_ = n & 255;
            ushort* dst = dstbase + ((size_t)(b_*H + h_)*D + w_)*T + t0base + cc;
            *(uint4*)(dst)      = a0;
            *(uint4*)(dst + 8)  = a1;
            *(uint4*)(dst + 16) = a2;
            *(uint4*)(dst + 24) = a3;
        }
    }
}

// ---- K2: E = exp(-SCALE*(2*sum max(q,k) - Qsum - Ksum)); E, Et, rsum, csum -
// 128x128 tile, 8x8/thread. Direct E/Et stores. Grid (4,4,32)=512 blocks.
__global__ __launch_bounds__(256, 2) void k2_scores(const ushort* __restrict__ qT,
        const ushort* __restrict__ xh, const uint* __restrict__ wkh,
        const float* __restrict__ Qsum, const float* __restrict__ Ksum,
        ushort* __restrict__ E, ushort* __restrict__ Et,
        float* __restrict__ rsum, float* __restrict__ csum) {
    __shared__ uint Qs[32*132];   // [up][128 t + pad]
    __shared__ uint Ks[32*132];   // [up][128 d + pad]
    __shared__ float cspart[128];
    int s0 = blockIdx.x*128, d0 = blockIdx.y*128, bh = blockIdx.z;
    int b_ = bh>>3, h_ = bh&7;
    int tid = threadIdx.x, tx = tid&15, ty = tid>>4;
    const ushort* qbb = qT + (size_t)bh*D*T;
    const ushort* xbb = xh + (size_t)b_*T*D;
    if (tid < 128) cspart[tid] = 0.f;
    int rp = tid>>3, tc = (tid&7)*16;   // Q staging: w-pair row, t-chunk
    int dr = tid>>1, cw = (tid&1)*32;   // K staging: d-row, 32-w chunk
    float accf[8][8] = {};
    for (int c = 0; c < 4; ++c) {
        int w0 = c*64;
        if (c) __syncthreads();
        {   // Q stage: rows (w0+2rp, +1) from [bh][w][t], pair-pack along w
            const ushort* qr = &qbb[(size_t)(w0+2*rp)*T + s0 + tc];
            uint4 a0 = *(const uint4*)qr,     a1 = *(const uint4*)(qr+8);
            uint4 b0 = *(const uint4*)(qr+T), b1 = *(const uint4*)(qr+T+8);
            uint av[8] = {a0.x,a0.y,a0.z,a0.w,a1.x,a1.y,a1.z,a1.w};
            uint bv[8] = {b0.x,b0.y,b0.z,b0.w,b1.x,b1.y,b1.z,b1.w};
            uint o[16];
            #pragma unroll
            for (int j = 0; j < 8; ++j) {
                o[2*j]   = __builtin_amdgcn_perm(bv[j], av[j], 0x05040100u);
                o[2*j+1] = __builtin_amdgcn_perm(bv[j], av[j], 0x07060302u);
            }
            uint* qd = &Qs[rp*132 + tc];
            *(uint4*)(qd)    = make_uint4(o[0],o[1],o[2],o[3]);
            *(uint4*)(qd+4)  = make_uint4(o[4],o[5],o[6],o[7]);
            *(uint4*)(qd+8)  = make_uint4(o[8],o[9],o[10],o[11]);
            *(uint4*)(qd+12) = make_uint4(o[12],o[13],o[14],o[15]);
        }
        {   // K stage: k = f16(x*wk); x rows are w-contiguous -> natural pairs
            const ushort* xr = &xbb[(size_t)(d0+dr)*D + w0 + cw];
            uint4 x0 = *(const uint4*)xr,      x1 = *(const uint4*)(xr+8);
            uint4 x2 = *(const uint4*)(xr+16), x3 = *(const uint4*)(xr+24);
            const uint* wp = &wkh[h_*128 + ((w0+cw)>>1)];
            uint4 w0v = *(const uint4*)wp,     w1v = *(const uint4*)(wp+4);
            uint4 w2v = *(const uint4*)(wp+8), w3v = *(const uint4*)(wp+12);
            uint xs[16] = {x0.x,x0.y,x0.z,x0.w, x1.x,x1.y,x1.z,x1.w,
                           x2.x,x2.y,x2.z,x2.w, x3.x,x3.y,x3.z,x3.w};
            uint ws[16] = {w0v.x,w0v.y,w0v.z,w0v.w, w1v.x,w1v.y,w1v.z,w1v.w,
                           w2v.x,w2v.y,w2v.z,w2v.w, w3v.x,w3v.y,w3v.z,w3v.w};
            int u0 = cw>>1;
            #pragma unroll
            for (int j = 0; j < 16; ++j)
                Ks[(u0+j)*132 + dr] = hmul2u(xs[j], ws[j]);
        }
        __syncthreads();
        uint acc2[8][8];
        #pragma unroll
        for (int i = 0; i < 8; ++i)
            #pragma unroll
            for (int j = 0; j < 8; ++j) acc2[i][j] = 0u;
        #pragma unroll 2
        for (int up = 0; up < 32; ++up) {
            const uint* qp = &Qs[up*132 + ty*8];
            uint4 qA = *(const uint4*)qp, qB = *(const uint4*)(qp+4);
            const uint* kp = &Ks[up*132 + tx*8];
            uint4 kA = *(const uint4*)kp, kB = *(const uint4*)(kp+4);
            uint q8[8] = {qA.x,qA.y,qA.z,qA.w, qB.x,qB.y,qB.z,qB.w};
            uint k8[8] = {kA.x,kA.y,kA.z,kA.w, kB.x,kB.y,kB.z,kB.w};
            #pragma unroll
            for (int i = 0; i < 8; ++i)
                #pragma unroll
                for (int j = 0; j < 8; ++j)
                    acc2[i][j] = hadd2u(acc2[i][j], hmax2u(q8[i], k8[j]));
        }
        #pragma unroll
        for (int i = 0; i < 8; ++i)
            #pragma unroll
            for (int j = 0; j < 8; ++j)
                accf[i][j] += h2lo(acc2[i][j]) + h2hi(acc2[i][j]);
    }
    // ---- epilogue: e = exp(-SCALE*(2M - Qsum - Ksum)) ----
    float qs8[8], ks8[8];
    {
        float4 qlo = *(const float4*)&Qsum[bh*T + s0 + ty*8];
        float4 qhi = *(const float4*)&Qsum[bh*T + s0 + ty*8 + 4];
        qs8[0]=qlo.x; qs8[1]=qlo.y; qs8[2]=qlo.z; qs8[3]=qlo.w;
        qs8[4]=qhi.x; qs8[5]=qhi.y; qs8[6]=qhi.z; qs8[7]=qhi.w;
        float4 klo = *(const float4*)&Ksum[bh*T + d0 + tx*8];
        float4 khi = *(const float4*)&Ksum[bh*T + d0 + tx*8 + 4];
        ks8[0]=klo.x; ks8[1]=klo.y; ks8[2]=klo.z; ks8[3]=klo.w;
        ks8[4]=khi.x; ks8[5]=khi.y; ks8[6]=khi.z; ks8[7]=khi.w;
    }
    #pragma unroll
    for (int i = 0; i < 8; ++i)
        #pragma unroll
        for (int j = 0; j < 8; ++j)
            accf[i][j] = __expf(-SCALE * (2.f*accf[i][j] - qs8[i] - ks8[j]));
    #pragma unroll
    for (int i = 0; i < 8; ++i) {
        ushort* ep = &E[((size_t)bh*T + s0 + ty*8 + i)*T + d0 + tx*8];
        *(ushort4*)ep     = make_ushort4(f2b(accf[i][0]), f2b(accf[i][1]), f2b(accf[i][2]), f2b(accf[i][3]));
        *(ushort4*)(ep+4) = make_ushort4(f2b(accf[i][4]), f2b(accf[i][5]), f2b(accf[i][6]), f2b(accf[i][7]));
    }
    #pragma unroll
    for (int j = 0; j < 8; ++j) {
        ushort* tp = &Et[((size_t)bh*T + d0 + tx*8 + j)*T + s0 + ty*8];
        *(ushort4*)tp     = make_ushort4(f2b(accf[0][j]), f2b(accf[1][j]), f2b(accf[2][j]), f2b(accf[3][j]));
        *(ushort4*)(tp+4) = make_ushort4(f2b(accf[4][j]), f2b(accf[5][j]), f2b(accf[6][j]), f2b(accf[7][j]));
    }
    #pragma unroll
    for (int i = 0; i < 8; ++i) {
        float rs = accf[i][0]+accf[i][1]+accf[i][2]+accf[i][3]
                 + accf[i][4]+accf[i][5]+accf[i][6]+accf[i][7];
        rs += __shfl_xor(rs, 1); rs += __shfl_xor(rs, 2);
        rs += __shfl_xor(rs, 4); rs += __shfl_xor(rs, 8);
        if ((tid & 15) == 0) atomicAdd(&rsum[bh*T + s0 + ty*8 + i], rs);
    }
    #pragma unroll
    for (int j = 0; j < 8; ++j) {
        float cs = 0.f;
        #pragma unroll
        for (int i = 0; i < 8; ++i) cs += accf[i][j];
        atomicAdd(&cspart[tx*8 + j], cs);
    }
    __syncthreads();
    if (tid < 128) atomicAdd(&csum[bh*T + d0 + tid], cspart[tid]);
}

// ---- K4: dual bf16 MFMA GEMM, 128x128 tile, 512 threads, reg-prefetch ------
// part head-sum accumulated directly into zacc via atomicAdd.
__global__ __launch_bounds__(512) void k4_attn(const ushort* __restrict__ E,
        const ushort* __restrict__ Et, const ushort* __restrict__ vfT,
        const ushort* __restrict__ vbT, const float* __restrict__ rsum,
        const float* __restrict__ csum, float* __restrict__ zacc) {
    __shared__ ushort A1[128*40];
    __shared__ ushort A2[128*40];
    __shared__ ushort Bf[128*40];
    __shared__ ushort Bb[128*40];
    int d0 = blockIdx.x * 128, w0 = blockIdx.y * 128, bh = blockIdx.z;
    const ushort* Ebb = E  + (size_t)bh*T*T;
    const ushort* Etb = Et + (size_t)bh*T*T;
    const ushort* vfb = vfT + (size_t)bh*D*T;
    const ushort* vbb = vbT + (size_t)bh*D*T;
    int tid = threadIdx.x, lane = tid & 63, wave = tid >> 6;
    int wm = wave >> 2, wn = wave & 3;          // 2 (d) x 4 (w) wave grid
    int sr = tid >> 2, sc = (tid & 3) * 8;
    int fr = lane & 15, fg = (lane >> 4) * 8;
    f32x4 acc1[4][2] = {}, acc2[4][2] = {};
    uint4 p1, p2, pf, pb;
    p1 = *(const uint4*)&Etb[(size_t)(d0+sr)*T + sc];
    p2 = *(const uint4*)&Ebb[(size_t)(d0+sr)*T + sc];
    pf = *(const uint4*)&vfb[(size_t)(w0+sr)*T + sc];
    pb = *(const uint4*)&vbb[(size_t)(w0+sr)*T + sc];
    for (int s0 = 0; s0 < T; s0 += 32) {
        *(uint4*)&A1[sr*40 + sc] = p1;
        *(uint4*)&A2[sr*40 + sc] = p2;
        *(uint4*)&Bf[sr*40 + sc] = pf;
        *(uint4*)&Bb[sr*40 + sc] = pb;
        __syncthreads();
        if (s0 + 32 < T) {   // prefetch next chunk under MFMA phase
            p1 = *(const uint4*)&Etb[(size_t)(d0+sr)*T + s0+32 + sc];
            p2 = *(const uint4*)&Ebb[(size_t)(d0+sr)*T + s0+32 + sc];
            pf = *(const uint4*)&vfb[(size_t)(w0+sr)*T + s0+32 + sc];
            pb = *(const uint4*)&vbb[(size_t)(w0+sr)*T + s0+32 + sc];
        }
        bf16x8 a1[4], a2[4], bfv[2], bbv[2];
        #pragma unroll
        for (int i = 0; i < 4; ++i) {
            a1[i] = *(const bf16x8*)&A1[(wm*64 + i*16 + fr)*40 + fg];
            a2[i] = *(const bf16x8*)&A2[(wm*64 + i*16 + fr)*40 + fg];
        }
        #pragma unroll
        for (int i = 0; i < 2; ++i) {
            bfv[i] = *(const bf16x8*)&Bf[(wn*32 + i*16 + fr)*40 + fg];
            bbv[i] = *(const bf16x8*)&Bb[(wn*32 + i*16 + fr)*40 + fg];
        }
        #pragma unroll
        for (int mi = 0; mi < 4; ++mi)
            #pragma unroll
            for (int ni = 0; ni < 2; ++ni) {
                acc1[mi][ni] = __builtin_amdgcn_mfma_f32_16x16x32_bf16(a1[mi], bfv[ni], acc1[mi][ni], 0, 0, 0);
                acc2[mi][ni] = __builtin_amdgcn_mfma_f32_16x16x32_bf16(a2[mi], bbv[ni], acc2[mi][ni], 0, 0, 0);
            }
        __syncthreads();
    }
    int fq = lane >> 4;
    float* zb = zacc + (size_t)(bh >> 3) * T * D;
    #pragma unroll
    for (int mi = 0; mi < 4; ++mi)
        #pragma unroll
        for (int r = 0; r < 4; ++r) {
            int d = d0 + wm*64 + mi*16 + fq*4 + r;
            float ic = 1.f / csum[bh*T + d];
            float ir = 1.f / rsum[bh*T + d];
            #pragma unroll
            for (int ni = 0; ni < 2; ++ni) {
                int w = w0 + wn*32 + ni*16 + fr;
                atomicAdd(&zb[(size_t)d*D + w], acc1[mi][ni][r]*ic + acc2[mi][ni][r]*ir);
            }
        }
}

// ---- K5: out = x + silu(zacc) @ fanin_w^T + fanin_b ------------------------
__global__ __launch_bounds__(256) void k5_fanin(const float* __restrict__ zacc,
        const float* __restrict__ fw, const float* __restrict__ fb,
        const float* __restrict__ x, float* __restrict__ out) {
    __shared__ float As[64][33];
    __shared__ float Bs[32][68];
    int bm = blockIdx.x * 64;
    int bn = blockIdx.y * 64;
    int tid = threadIdx.x;
    int tx = tid & 15, ty = tid >> 4;
    float acc[4][4] = {};
    for (int k0 = 0; k0 < 256; k0 += 32) {
        int r = tid >> 3, c4 = (tid & 7) * 4;
        for (int rr = r; rr < 64; rr += 32) {
            float4 v = *(const float4*)&zacc[(size_t)(bm + rr) * 256 + k0 + c4];
            As[rr][c4+0] = v.x / (1.f + __expf(-1.702f*v.x));
            As[rr][c4+1] = v.y / (1.f + __expf(-1.702f*v.y));
            As[rr][c4+2] = v.z / (1.f + __expf(-1.702f*v.z));
            As[rr][c4+3] = v.w / (1.f + __expf(-1.702f*v.w));
        }
        for (int nn = r; nn < 64; nn += 32) {
            float4 v = *(const float4*)&fw[(size_t)(bn + nn) * 256 + k0 + c4];
            Bs[c4+0][nn]=v.x; Bs[c4+1][nn]=v.y; Bs[c4+2][nn]=v.z; Bs[c4+3][nn]=v.w;
        }
        __syncthreads();
        for (int kk = 0; kk < 32; ++kk) {
            float a[4];
            #pragma unroll
            for (int i=0;i<4;++i) a[i] = As[ty*4+i][kk];
            float4 bv = *(const float4*)&Bs[kk][tx*4];
            #pragma unroll
            for (int i=0;i<4;++i) {
                acc[i][0] += a[i]*bv.x; acc[i][1] += a[i]*bv.y;
                acc[i][2] += a[i]*bv.z; acc[i][3] += a[i]*bv.w;
            }
        }
        __syncthreads();
    }
    #pragma unroll
    for (int i=0;i<4;++i) {
        int m = bm + ty*4 + i;
        int n = bn + tx*4;
        float4 xv = *(const float4*)&x[(size_t)m*256 + n];
        float4 v;
        v.x = acc[i][0] + fb[n+0] + xv.x;
        v.y = acc[i][1] + fb[n+1] + xv.y;
        v.z = acc[i][2] + fb[n+2] + xv.z;
        v.w = acc[i][3] + fb[n+3] + xv.w;
        *(float4*)&out[(size_t)m*256 + n] = v;
    }
}

extern "C" void kernel_launch(void* const* d_in, const int* in_sizes, int n_in,
                              void* d_out, int out_size, void* d_ws, size_t ws_size,
                              hipStream_t stream) {
    const float* x       = (const float*)d_in[0];
    const float* wk      = (const float*)d_in[1];
    const float* wqv_w   = (const float*)d_in[2];
    const float* wqv_b   = (const float*)d_in[3];
    const float* fanin_w = (const float*)d_in[4];
    const float* fanin_b = (const float*)d_in[5];
    char* wsb = (char*)d_ws;
    ushort* xb   = (ushort*)(wsb);                 // 1,048,576 B (bf16 x)
    ushort* wqvb = (ushort*)(wsb + 1048576);       // 3,145,728  (bf16 wqv)
    ushort* qTb  = (ushort*)(wsb + 4194304);       // 8,388,608  q f16 [bh][w][t]
    ushort* vfT  = (ushort*)(wsb + 12582912);      // 8,388,608  bf16 [bh][w][t]
    ushort* vbT  = (ushort*)(wsb + 20971520);      // 8,388,608
    ushort* Eb   = (ushort*)(wsb + 29360128);      // 16,777,216 bf16 [bh][s][d]
    ushort* Etb  = (ushort*)(wsb + 46137344);      // 16,777,216 bf16 [bh][d][s]
    float*  rsum = (float*)(wsb + 62914560);       // 65,536 (rsum+csum contiguous)
    float*  csum = (float*)(wsb + 62980096);       // 65,536
    ushort* xh   = (ushort*)(wsb + 63045632);      // 1,048,576  f16 x
    ushort* wkh  = (ushort*)(wsb + 64094208);      // 4,096      f16 wk
    float*  Qsum = (float*)(wsb + 64098304);       // 65,536
    float*  Ksum = (float*)(wsb + 64163840);       // 65,536
    float*  zacc = (float*)(wsb + 79822848);       // 2,097,152  head-summed bo
    float* out   = (float*)d_out;

    k0_fused  <<<6146, 256, 0, stream>>>(x, wqv_w, wk, xb, xh, wqvb, (ushort*)wkh, rsum, Qsum, zacc, Ksum);
    k1_qkv    <<<dim3(16, 48), 256, 0, stream>>>(xb, wqvb, wqv_b, qTb, vfT, vbT, Qsum);
    k2_scores <<<dim3(4, 4, 32), 256, 0, stream>>>(qTb, xh, (const uint*)wkh, Qsum, Ksum, Eb, Etb, rsum, csum);
    k4_attn   <<<dim3(4, 2, 32), 512, 0, stream>>>(Eb, Etb, vfT, vbT, rsum, csum, zacc);
    k5_fanin  <<<dim3(32, 4), 256, 0, stream>>>(zacc, fanin_w, fanin_b, x, out);
}

// Round 10
// 179.995 us; speedup vs baseline: 1.3350x; 1.3054x over previous
//
#include <hip/hip_runtime.h>
#include <hip/hip_bf16.h>
#include <math.h>

#define B 4
#define T 512
#define D 256
#define H 8
#define BH (B*H)
#define SCALE 0.0625f
// u8 quantization: value = (u - 128) / 1024; score = -SCALE/1024 * SAD
#define QSCALE 1024.0f
#define SADF 6.103515625e-5f

typedef float f32x4 __attribute__((ext_vector_type(4)));
typedef short bf16x8 __attribute__((ext_vector_type(8)));

__device__ __forceinline__ ushort f2b(float f) {
    __hip_bfloat16 h = __float2bfloat16(f);
    return *reinterpret_cast<ushort*>(&h);
}
__device__ __forceinline__ uint sadacc(uint a, uint b, uint c) {
    uint d;
    asm("v_sad_u8 %0, %1, %2, %3" : "=v"(d) : "v"(a), "v"(b), "v"(c));
    return d;
}
__device__ __forceinline__ uint quant8(float v) {
    return (uint)fminf(fmaxf(fmaf(v, QSCALE, 128.5f), 0.f), 255.f);
}

// ---- K0 (fused): x->bf16, wqv->bf16, ku8[bh][d][w] = quant(x*wk), zeroing ---
__global__ __launch_bounds__(256) void k0_fused(const float* __restrict__ x,
        const float* __restrict__ w, const float* __restrict__ wk,
        ushort* __restrict__ xb, ushort* __restrict__ wb,
        uchar* __restrict__ ku8, float* __restrict__ rszero,
        float* __restrict__ zacc) {
    int bx = blockIdx.x;
    if (bx < 2048) {
        if (bx < 32) {          // zero rsum+csum (32768 floats)
            ((float4*)rszero)[bx*256 + threadIdx.x] = make_float4(0.f,0.f,0.f,0.f);
        } else if (bx < 544) {  // zero zacc (524288 floats)
            ((float4*)zacc)[(bx-32)*256 + threadIdx.x] = make_float4(0.f,0.f,0.f,0.f);
        }
        int i = bx * 256 + threadIdx.x;
        if (i < 131072) {
            float4 v = ((const float4*)x)[i];
            ((ushort4*)xb)[i] = make_ushort4(f2b(v.x), f2b(v.y), f2b(v.z), f2b(v.w));
        } else {
            int j = i - 131072;   // < 393216
            float4 v = ((const float4*)w)[j];
            ((ushort4*)wb)[j] = make_ushort4(f2b(v.x), f2b(v.y), f2b(v.z), f2b(v.w));
        }
    } else {
        // ku8: 32 bh x 512 d x 256 w bytes; 16 bytes/thread
        int gid = (bx - 2048) * 256 + threadIdx.x;   // 0..262143
        int wq = (gid & 15) * 16;
        int d_ = (gid >> 4) & 511;
        int bh = gid >> 13;
        int b_ = bh >> 3, h_ = bh & 7;
        const float4* xr = (const float4*)&x[((size_t)(b_*T + d_))*D + wq];
        const float4* wr = (const float4*)&wk[h_*D + wq];
        uint out[4];
        #pragma unroll
        for (int p = 0; p < 4; ++p) {
            float4 xv = xr[p];
            float4 wv = wr[p];
            uint u0 = quant8(xv.x*wv.x);
            uint u1 = quant8(xv.y*wv.y);
            uint u2 = quant8(xv.z*wv.z);
            uint u3 = quant8(xv.w*wv.w);
            out[p] = u0 | (u1<<8) | (u2<<16) | (u3<<24);
        }
        *(uint4*)&ku8[((size_t)bh*T + d_)*D + wq] = make_uint4(out[0],out[1],out[2],out[3]);
    }
}

// ---- K1: bf16 MFMA GEMM  v = x @ wqv^T + bias ------------------------------
// q -> u8 [bh][t][w] via LDS byte tile; vf/vb -> bf16 [bh][w][t] via transpose.
__global__ __launch_bounds__(256) void k1_qkv(const ushort* __restrict__ xb,
        const ushort* __restrict__ wb, const float* __restrict__ bias,
        uchar* __restrict__ qu8, ushort* __restrict__ vf, ushort* __restrict__ vb) {
    __shared__ ushort AB[2*128*40];
    ushort* As = AB;
    ushort* Bs = AB + 128*40;
    int tid = threadIdx.x;
    int lane = tid & 63, wave = tid >> 6;
    int wm = wave >> 1, wn = wave & 1;
    int bm0 = blockIdx.x * 128, bn0 = blockIdx.y * 128;
    f32x4 acc[4][4] = {};
    int sr = tid >> 2, sc = (tid & 3) * 8;
    int fr = lane & 15, fg = (lane >> 4) * 8;
    for (int k0 = 0; k0 < 256; k0 += 32) {
        *(uint4*)&As[sr*40 + sc]      = *(const uint4*)&xb[(size_t)(bm0+sr)*256 + k0 + sc];
        *(uint4*)&As[(sr+64)*40 + sc] = *(const uint4*)&xb[(size_t)(bm0+sr+64)*256 + k0 + sc];
        *(uint4*)&Bs[sr*40 + sc]      = *(const uint4*)&wb[(size_t)(bn0+sr)*256 + k0 + sc];
        *(uint4*)&Bs[(sr+64)*40 + sc] = *(const uint4*)&wb[(size_t)(bn0+sr+64)*256 + k0 + sc];
        __syncthreads();
        bf16x8 af[4], bfv[4];
        #pragma unroll
        for (int i = 0; i < 4; ++i)
            af[i] = *(const bf16x8*)&As[(wm*64 + i*16 + fr)*40 + fg];
        #pragma unroll
        for (int i = 0; i < 4; ++i)
            bfv[i] = *(const bf16x8*)&Bs[(wn*64 + i*16 + fr)*40 + fg];
        #pragma unroll
        for (int mi = 0; mi < 4; ++mi)
            #pragma unroll
            for (int ni = 0; ni < 4; ++ni)
                acc[mi][ni] = __builtin_amdgcn_mfma_f32_16x16x32_bf16(af[mi], bfv[ni], acc[mi][ni], 0, 0, 0);
        __syncthreads();
    }
    int fq = lane >> 4;
    int g = bn0 >> 11;
    int b_ = bm0 >> 9;
    int t0base = bm0 & 511;
    float bn_[4];
    #pragma unroll
    for (int ni = 0; ni < 4; ++ni) bn_[ni] = bias[bn0 + wn*64 + ni*16 + fr];

    if (g == 0) {
        // q path: quantize to u8, LDS tile [128 m][144 n], coalesced byte rows out
        uchar* tb8 = (uchar*)AB;
        #pragma unroll
        for (int ni = 0; ni < 4; ++ni) {
            int nloc = wn*64 + ni*16 + fr;
            #pragma unroll
            for (int mi = 0; mi < 4; ++mi) {
                #pragma unroll
                for (int r = 0; r < 4; ++r) {
                    int mloc = wm*64 + mi*16 + fq*4 + r;
                    tb8[mloc*144 + nloc] = (uchar)quant8(acc[mi][ni][r] + bn_[ni]);
                }
            }
        }
        __syncthreads();
        int row = tid >> 1;
        int half = (tid & 1) * 64;
        const uchar* src = &tb8[row*144 + half];
        uint4 a0 = *(const uint4*)(src);
        uint4 a1 = *(const uint4*)(src + 16);
        uint4 a2 = *(const uint4*)(src + 32);
        uint4 a3 = *(const uint4*)(src + 48);
        int h_ = bn0 >> 8;
        int woff = bn0 & 255;
        uchar* dst = qu8 + ((size_t)(b_*H + h_)*T + t0base + row)*D + woff + half;
        *(uint4*)(dst)      = a0;
        *(uint4*)(dst + 16) = a1;
        *(uint4*)(dst + 32) = a2;
        *(uint4*)(dst + 48) = a3;
    } else {
        // vf/vb path: bf16, transposed [bh][w][t] via LDS (coalesced stores)
        ushort* dstbase = (g == 1) ? vf : vb;
        ushort* tb = AB;
        #pragma unroll
        for (int hf = 0; hf < 2; ++hf) {
            __syncthreads();
            if (wn == hf) {
                #pragma unroll
                for (int ni = 0; ni < 4; ++ni) {
                    int nh = ni*16 + fr;
                    #pragma unroll
                    for (int mi = 0; mi < 4; ++mi) {
                        int mloc = wm*64 + mi*16 + fq*4;
                        *(ushort4*)&tb[nh*132 + mloc] = make_ushort4(
                            f2b(acc[mi][ni][0] + bn_[ni]), f2b(acc[mi][ni][1] + bn_[ni]),
                            f2b(acc[mi][ni][2] + bn_[ni]), f2b(acc[mi][ni][3] + bn_[ni]));
                    }
                }
            }
            __syncthreads();
            {   // 4 threads per n-row, 64B contiguous each
                int rr = tid >> 2;
                int cc = (tid & 3) * 32;
                const ushort* src = &tb[rr*132 + cc];
                uint4 a0 = *(const uint4*)(src);
                uint4 a1 = *(const uint4*)(src + 8);
                uint4 a2 = *(const uint4*)(src + 16);
                uint4 a3 = *(const uint4*)(src + 24);
                int n = bn0 + hf*64 + rr;
                int h_ = (n & 2047) >> 8, w_ = n & 255;
                ushort* dst = dstbase + ((size_t)(b_*H + h_)*D + w_)*T + t0base + cc;
                *(uint4*)(dst)      = a0;
                *(uint4*)(dst + 8)  = a1;
                *(uint4*)(dst + 16) = a2;
                *(uint4*)(dst + 24) = a3;
            }
        }
    }
}

// ---- K2: SAD-based scores. E = exp(-SADF * SAD(qu8, ku8)); E, Et, rsum, csum
// 128x128 tile, 8x8/thread, v_sad_u8 inner: 4 elems/inst. 2 w-chunks, 3 barriers.
__global__ __launch_bounds__(256) void k2_scores(const uchar* __restrict__ qu8,
        const uchar* __restrict__ ku8, ushort* __restrict__ E, ushort* __restrict__ Et,
        float* __restrict__ rsum, float* __restrict__ csum) {
    __shared__ uint Qs[32*132];   // [wp][128 t + pad]
    __shared__ uint Ks[32*132];   // [wp][128 d + pad]
    __shared__ float cspart[128];
    int s0 = blockIdx.x*128, d0 = blockIdx.y*128, bh = blockIdx.z;
    int tid = threadIdx.x, tx = tid&15, ty = tid>>4;
    const uchar* qb = qu8 + (size_t)bh*T*D;
    const uchar* kb = ku8 + (size_t)bh*T*D;
    if (tid < 128) cspart[tid] = 0.f;
    int row = tid >> 1;            // 0..127 staging row
    int hoff = (tid & 1) * 64;     // 64B half of the 128B chunk-row
    int wpb = (tid & 1) * 16;      // pack base within chunk
    uint acc32[8][8];
    #pragma unroll
    for (int i = 0; i < 8; ++i)
        #pragma unroll
        for (int j = 0; j < 8; ++j) acc32[i][j] = 0u;
    uint4 qv[4], kv[4];
    {   // chunk 0 loads (w 0..127)
        const uchar* qs = &qb[(size_t)(s0+row)*D + hoff];
        qv[0] = *(const uint4*)qs;      qv[1] = *(const uint4*)(qs+16);
        qv[2] = *(const uint4*)(qs+32); qv[3] = *(const uint4*)(qs+48);
        const uchar* ks = &kb[(size_t)(d0+row)*D + hoff];
        kv[0] = *(const uint4*)ks;      kv[1] = *(const uint4*)(ks+16);
        kv[2] = *(const uint4*)(ks+32); kv[3] = *(const uint4*)(ks+48);
    }
    #pragma unroll
    for (int c = 0; c < 2; ++c) {
        #pragma unroll
        for (int p = 0; p < 4; ++p) {
            Qs[(wpb+p*4+0)*132 + row] = qv[p].x;
            Qs[(wpb+p*4+1)*132 + row] = qv[p].y;
            Qs[(wpb+p*4+2)*132 + row] = qv[p].z;
            Qs[(wpb+p*4+3)*132 + row] = qv[p].w;
            Ks[(wpb+p*4+0)*132 + row] = kv[p].x;
            Ks[(wpb+p*4+1)*132 + row] = kv[p].y;
            Ks[(wpb+p*4+2)*132 + row] = kv[p].z;
            Ks[(wpb+p*4+3)*132 + row] = kv[p].w;
        }
        __syncthreads();
        if (c == 0) {   // prefetch chunk 1 (w 128..255) under compute
            const uchar* qs = &qb[(size_t)(s0+row)*D + 128 + hoff];
            qv[0] = *(const uint4*)qs;      qv[1] = *(const uint4*)(qs+16);
            qv[2] = *(const uint4*)(qs+32); qv[3] = *(const uint4*)(qs+48);
            const uchar* ks = &kb[(size_t)(d0+row)*D + 128 + hoff];
            kv[0] = *(const uint4*)ks;      kv[1] = *(const uint4*)(ks+16);
            kv[2] = *(const uint4*)(ks+32); kv[3] = *(const uint4*)(ks+48);
        }
        #pragma unroll 4
        for (int wp = 0; wp < 32; ++wp) {
            const uint* qp = &Qs[wp*132 + ty*8];
            uint4 qA = *(const uint4*)qp, qB = *(const uint4*)(qp+4);
            const uint* kp = &Ks[wp*132 + tx*8];
            uint4 kA = *(const uint4*)kp, kB = *(const uint4*)(kp+4);
            uint q8[8] = {qA.x,qA.y,qA.z,qA.w, qB.x,qB.y,qB.z,qB.w};
            uint k8[8] = {kA.x,kA.y,kA.z,kA.w, kB.x,kB.y,kB.z,kB.w};
            #pragma unroll
            for (int i = 0; i < 8; ++i)
                #pragma unroll
                for (int j = 0; j < 8; ++j)
                    acc32[i][j] = sadacc(q8[i], k8[j], acc32[i][j]);
        }
        if (c == 0) __syncthreads();
    }
    // ---- epilogue: e = exp(-SADF * acc) ----
    float accf[8][8];
    #pragma unroll
    for (int i = 0; i < 8; ++i)
        #pragma unroll
        for (int j = 0; j < 8; ++j)
            accf[i][j] = __expf(-SADF * (float)acc32[i][j]);
    #pragma unroll
    for (int i = 0; i < 8; ++i) {
        ushort* ep = &E[((size_t)bh*T + s0 + ty*8 + i)*T + d0 + tx*8];
        *(ushort4*)ep     = make_ushort4(f2b(accf[i][0]), f2b(accf[i][1]), f2b(accf[i][2]), f2b(accf[i][3]));
        *(ushort4*)(ep+4) = make_ushort4(f2b(accf[i][4]), f2b(accf[i][5]), f2b(accf[i][6]), f2b(accf[i][7]));
    }
    #pragma unroll
    for (int j = 0; j < 8; ++j) {
        ushort* tp = &Et[((size_t)bh*T + d0 + tx*8 + j)*T + s0 + ty*8];
        *(ushort4*)tp     = make_ushort4(f2b(accf[0][j]), f2b(accf[1][j]), f2b(accf[2][j]), f2b(accf[3][j]));
        *(ushort4*)(tp+4) = make_ushort4(f2b(accf[4][j]), f2b(accf[5][j]), f2b(accf[6][j]), f2b(accf[7][j]));
    }
    #pragma unroll
    for (int i = 0; i < 8; ++i) {
        float rs = accf[i][0]+accf[i][1]+accf[i][2]+accf[i][3]
                 + accf[i][4]+accf[i][5]+accf[i][6]+accf[i][7];
        rs += __shfl_xor(rs, 1); rs += __shfl_xor(rs, 2);
        rs += __shfl_xor(rs, 4); rs += __shfl_xor(rs, 8);
        if ((tid & 15) == 0) atomicAdd(&rsum[bh*T + s0 + ty*8 + i], rs);
    }
    #pragma unroll
    for (int j = 0; j < 8; ++j) {
        float cs = 0.f;
        #pragma unroll
        for (int i = 0; i < 8; ++i) cs += accf[i][j];
        atomicAdd(&cspart[tx*8 + j], cs);
    }
    __syncthreads();
    if (tid < 128) atomicAdd(&csum[bh*T + d0 + tid], cspart[tid]);
}

// ---- K4: dual bf16 MFMA GEMM, 128x128 tile, 512 threads, reg-prefetch ------
__global__ __launch_bounds__(512) void k4_attn(const ushort* __restrict__ E,
        const ushort* __restrict__ Et, const ushort* __restrict__ vfT,
        const ushort* __restrict__ vbT, const float* __restrict__ rsum,
        const float* __restrict__ csum, float* __restrict__ zacc) {
    __shared__ ushort A1[128*40];
    __shared__ ushort A2[128*40];
    __shared__ ushort Bf[128*40];
    __shared__ ushort Bb[128*40];
    int d0 = blockIdx.x * 128, w0 = blockIdx.y * 128, bh = blockIdx.z;
    const ushort* Ebb = E  + (size_t)bh*T*T;
    const ushort* Etb = Et + (size_t)bh*T*T;
    const ushort* vfb = vfT + (size_t)bh*D*T;
    const ushort* vbb = vbT + (size_t)bh*D*T;
    int tid = threadIdx.x, lane = tid & 63, wave = tid >> 6;
    int wm = wave >> 2, wn = wave & 3;
    int sr = tid >> 2, sc = (tid & 3) * 8;
    int fr = lane & 15, fg = (lane >> 4) * 8;
    f32x4 acc1[4][2] = {}, acc2[4][2] = {};
    uint4 p1, p2, pf, pb;
    p1 = *(const uint4*)&Etb[(size_t)(d0+sr)*T + sc];
    p2 = *(const uint4*)&Ebb[(size_t)(d0+sr)*T + sc];
    pf = *(const uint4*)&vfb[(size_t)(w0+sr)*T + sc];
    pb = *(const uint4*)&vbb[(size_t)(w0+sr)*T + sc];
    for (int s0 = 0; s0 < T; s0 += 32) {
        *(uint4*)&A1[sr*40 + sc] = p1;
        *(uint4*)&A2[sr*40 + sc] = p2;
        *(uint4*)&Bf[sr*40 + sc] = pf;
        *(uint4*)&Bb[sr*40 + sc] = pb;
        __syncthreads();
        if (s0 + 32 < T) {
            p1 = *(const uint4*)&Etb[(size_t)(d0+sr)*T + s0+32 + sc];
            p2 = *(const uint4*)&Ebb[(size_t)(d0+sr)*T + s0+32 + sc];
            pf = *(const uint4*)&vfb[(size_t)(w0+sr)*T + s0+32 + sc];
            pb = *(const uint4*)&vbb[(size_t)(w0+sr)*T + s0+32 + sc];
        }
        bf16x8 a1[4], a2[4], bfv[2], bbv[2];
        #pragma unroll
        for (int i = 0; i < 4; ++i) {
            a1[i] = *(const bf16x8*)&A1[(wm*64 + i*16 + fr)*40 + fg];
            a2[i] = *(const bf16x8*)&A2[(wm*64 + i*16 + fr)*40 + fg];
        }
        #pragma unroll
        for (int i = 0; i < 2; ++i) {
            bfv[i] = *(const bf16x8*)&Bf[(wn*32 + i*16 + fr)*40 + fg];
            bbv[i] = *(const bf16x8*)&Bb[(wn*32 + i*16 + fr)*40 + fg];
        }
        #pragma unroll
        for (int mi = 0; mi < 4; ++mi)
            #pragma unroll
            for (int ni = 0; ni < 2; ++ni) {
                acc1[mi][ni] = __builtin_amdgcn_mfma_f32_16x16x32_bf16(a1[mi], bfv[ni], acc1[mi][ni], 0, 0, 0);
                acc2[mi][ni] = __builtin_amdgcn_mfma_f32_16x16x32_bf16(a2[mi], bbv[ni], acc2[mi][ni], 0, 0, 0);
            }
        __syncthreads();
    }
    int fq = lane >> 4;
    float* zb = zacc + (size_t)(bh >> 3) * T * D;
    #pragma unroll
    for (int mi = 0; mi < 4; ++mi)
        #pragma unroll
        for (int r = 0; r < 4; ++r) {
            int d = d0 + wm*64 + mi*16 + fq*4 + r;
            float ic = 1.f / csum[bh*T + d];
            float ir = 1.f / rsum[bh*T + d];
            #pragma unroll
            for (int ni = 0; ni < 2; ++ni) {
                int w = w0 + wn*32 + ni*16 + fr;
                atomicAdd(&zb[(size_t)d*D + w], acc1[mi][ni][r]*ic + acc2[mi][ni][r]*ir);
            }
        }
}

// ---- K5: out = x + silu(zacc) @ fanin_w^T + fanin_b ------------------------
__global__ __launch_bounds__(256) void k5_fanin(const float* __restrict__ zacc,
        const float* __restrict__ fw, const float* __restrict__ fb,
        const float* __restrict__ x, float* __restrict__ out) {
    __shared__ float As[64][33];
    __shared__ float Bs[32][68];
    int bm = blockIdx.x * 64;
    int bn = blockIdx.y * 64;
    int tid = threadIdx.x;
    int tx = tid & 15, ty = tid >> 4;
    float acc[4][4] = {};
    for (int k0 = 0; k0 < 256; k0 += 32) {
        int r = tid >> 3, c4 = (tid & 7) * 4;
        for (int rr = r; rr < 64; rr += 32) {
            float4 v = *(const float4*)&zacc[(size_t)(bm + rr) * 256 + k0 + c4];
            As[rr][c4+0] = v.x / (1.f + __expf(-1.702f*v.x));
            As[rr][c4+1] = v.y / (1.f + __expf(-1.702f*v.y));
            As[rr][c4+2] = v.z / (1.f + __expf(-1.702f*v.z));
            As[rr][c4+3] = v.w / (1.f + __expf(-1.702f*v.w));
        }
        for (int nn = r; nn < 64; nn += 32) {
            float4 v = *(const float4*)&fw[(size_t)(bn + nn) * 256 + k0 + c4];
            Bs[c4+0][nn]=v.x; Bs[c4+1][nn]=v.y; Bs[c4+2][nn]=v.z; Bs[c4+3][nn]=v.w;
        }
        __syncthreads();
        for (int kk = 0; kk < 32; ++kk) {
            float a[4];
            #pragma unroll
            for (int i=0;i<4;++i) a[i] = As[ty*4+i][kk];
            float4 bv = *(const float4*)&Bs[kk][tx*4];
            #pragma unroll
            for (int i=0;i<4;++i) {
                acc[i][0] += a[i]*bv.x; acc[i][1] += a[i]*bv.y;
                acc[i][2] += a[i]*bv.z; acc[i][3] += a[i]*bv.w;
            }
        }
        __syncthreads();
    }
    #pragma unroll
    for (int i=0;i<4;++i) {
        int m = bm + ty*4 + i;
        int n = bn + tx*4;
        float4 xv = *(const float4*)&x[(size_t)m*256 + n];
        float4 v;
        v.x = acc[i][0] + fb[n+0] + xv.x;
        v.y = acc[i][1] + fb[n+1] + xv.y;
        v.z = acc[i][2] + fb[n+2] + xv.z;
        v.w = acc[i][3] + fb[n+3] + xv.w;
        *(float4*)&out[(size_t)m*256 + n] = v;
    }
}

extern "C" void kernel_launch(void* const* d_in, const int* in_sizes, int n_in,
                              void* d_out, int out_size, void* d_ws, size_t ws_size,
                              hipStream_t stream) {
    const float* x       = (const float*)d_in[0];
    const float* wk      = (const float*)d_in[1];
    const float* wqv_w   = (const float*)d_in[2];
    const float* wqv_b   = (const float*)d_in[3];
    const float* fanin_w = (const float*)d_in[4];
    const float* fanin_b = (const float*)d_in[5];
    char* wsb = (char*)d_ws;
    ushort* xb   = (ushort*)(wsb);                 // 1,048,576 B (bf16 x)
    ushort* wqvb = (ushort*)(wsb + 1048576);       // 3,145,728  (bf16 wqv)
    uchar*  qu8  = (uchar*)(wsb + 4194304);        // 4,194,304  q u8 [bh][t][w]
    ushort* vfT  = (ushort*)(wsb + 12582912);      // 8,388,608  bf16 [bh][w][t]
    ushort* vbT  = (ushort*)(wsb + 20971520);      // 8,388,608
    ushort* Eb   = (ushort*)(wsb + 29360128);      // 16,777,216 bf16 [bh][s][d]
    ushort* Etb  = (ushort*)(wsb + 46137344);      // 16,777,216 bf16 [bh][d][s]
    float*  rsum = (float*)(wsb + 62914560);       // 65,536 (rsum+csum contiguous)
    float*  csum = (float*)(wsb + 62980096);       // 65,536
    uchar*  ku8  = (uchar*)(wsb + 63045632);       // 4,194,304  k u8 [bh][d][w]
    float*  zacc = (float*)(wsb + 79822848);       // 2,097,152  head-summed bo
    float* out   = (float*)d_out;

    k0_fused  <<<3072, 256, 0, stream>>>(x, wqv_w, wk, xb, wqvb, ku8, rsum, zacc);
    k1_qkv    <<<dim3(16, 48), 256, 0, stream>>>(xb, wqvb, wqv_b, qu8, vfT, vbT);
    k2_scores <<<dim3(4, 4, 32), 256, 0, stream>>>(qu8, ku8, Eb, Etb, rsum, csum);
    k4_attn   <<<dim3(4, 2, 32), 512, 0, stream>>>(Eb, Etb, vfT, vbT, rsum, csum, zacc);
    k5_fanin  <<<dim3(32, 4), 256, 0, stream>>>(zacc, fanin_w, fanin_b, x, out);
}